// Round 9
// baseline (320.852 us; speedup 1.0000x reference)
//
#include <hip/hip_runtime.h>
#include <cstdint>

#define NB    8
#define NSEQ  4096
#define CDIM  256
#define NTOK  (NB*NSEQ)

typedef _Float16 half8  __attribute__((ext_vector_type(8)));
typedef _Float16 half4v __attribute__((ext_vector_type(4)));
typedef float    f32x4  __attribute__((ext_vector_type(4)));
typedef float    f32x16 __attribute__((ext_vector_type(16)));
typedef uint32_t u32x4  __attribute__((ext_vector_type(4)));

typedef unsigned int u32_g __attribute__((address_space(1)));
typedef unsigned int u32_l __attribute__((address_space(3)));

// direct global->LDS, 16B per lane; LDS dest = wave-uniform base + lane*16
__device__ __forceinline__ void gload_lds16(const void* g, void* l) {
  __builtin_amdgcn_global_load_lds((u32_g*)(uintptr_t)g,
                                   (u32_l*)(uint32_t)(uintptr_t)l, 16, 0, 0);
}

__device__ __forceinline__ uint32_t pkrtz(float a, float b) {
  auto h = __builtin_amdgcn_cvt_pkrtz(a, b);  // lo16 = a, hi16 = b
  return __builtin_bit_cast(uint32_t, h);
}
// lane^32 exchange via shfl (semantics-certain)
__device__ __forceinline__ float sx32f(float v) { return __shfl_xor(v, 32, 64); }
__device__ __forceinline__ uint32_t sx32u(uint32_t v) {
  return (uint32_t)__shfl_xor((int)v, 32, 64);
}

// ---------------- LayerNorm: one wave per token (C=256 = 64 lanes x float4)
__global__ __launch_bounds__(256) void ln_kernel(
    const float* __restrict__ x, const float* __restrict__ gam,
    const float* __restrict__ bet, float* __restrict__ xnf,
    _Float16* __restrict__ xnh) {
  const int lane = threadIdx.x & 63;
  const size_t tok = (size_t)blockIdx.x * 4 + (threadIdx.x >> 6);
  const float4 v = ((const float4*)(x + tok * CDIM))[lane];
  float s  = v.x + v.y + v.z + v.w;
  float s2 = v.x*v.x + v.y*v.y + v.z*v.z + v.w*v.w;
  #pragma unroll
  for (int m = 1; m < 64; m <<= 1) {
    s  += __shfl_xor(s,  m, 64);
    s2 += __shfl_xor(s2, m, 64);
  }
  const float mean = s * (1.0f / CDIM);
  const float rstd = rsqrtf(s2 * (1.0f / CDIM) - mean * mean + 1e-3f);
  const float4 gv = ((const float4*)gam)[lane];
  const float4 bv = ((const float4*)bet)[lane];
  float4 o;
  o.x = (v.x - mean) * rstd * gv.x + bv.x;
  o.y = (v.y - mean) * rstd * gv.y + bv.y;
  o.z = (v.z - mean) * rstd * gv.z + bv.z;
  o.w = (v.w - mean) * rstd * gv.w + bv.w;
  ((float4*)(xnf + tok * CDIM))[lane] = o;
  half4v h;
  h[0] = (_Float16)o.x; h[1] = (_Float16)o.y;
  h[2] = (_Float16)o.z; h[3] = (_Float16)o.w;
  ((half4v*)(xnh + tok * CDIM))[lane] = h;
}

// ---------------- projection GEMM (unchanged from R1)
__global__ __launch_bounds__(256, 2) void proj_kernel(
    const _Float16* __restrict__ inh,
    const float* __restrict__ wq_, const float* __restrict__ bq_,
    const float* __restrict__ wk_, const float* __restrict__ bk_,
    const float* __restrict__ wv_, const float* __restrict__ bv_,
    const float* __restrict__ wp_, const float* __restrict__ bp_,
    _Float16* __restrict__ qg, _Float16* __restrict__ kg, _Float16* __restrict__ vtg,
    const float* __restrict__ xnf, float* __restrict__ outf,
    int mode_base) {
  extern __shared__ char smem[];
  const int mode = mode_base + blockIdx.z;
  const float* wsel = (mode == 0) ? wq_ : (mode == 1) ? wk_ : (mode == 2) ? wv_ : wp_;
  const float* bsel = (mode == 0) ? bq_ : (mode == 1) ? bk_ : (mode == 2) ? bv_ : bp_;

  const int tid = threadIdx.x;
  const int lane = tid & 63;
  const int wid  = tid >> 6;     // 0..3
  const int g    = lane >> 4;    // 0..3
  const int lr   = lane & 15;
  const int jstrip = blockIdx.y; // 0..3
  const size_t tok0 = (size_t)blockIdx.x * 512;

  char* wt   = smem;             // [64 j][256 c] f16, XOR-swizzled (32KB)
  char* tile = smem + 32768;     // [64 tok][256 c] f16, swizzled (32KB)

  for (int i = 0; i < 64; ++i) {
    int idx = i * 256 + tid;
    int c = idx >> 6, j = idx & 63;
    float val = wsel[(size_t)c * CDIM + jstrip * 64 + j];
    *(_Float16*)(wt + j * 512 + ((((c >> 3) ^ (j & 7))) << 4) + ((c & 7) << 1)) =
        (_Float16)val;
  }
  float bjv[4];
  #pragma unroll
  for (int jc = 0; jc < 4; ++jc) bjv[jc] = bsel[jstrip * 64 + jc * 16 + lr];
  __syncthreads();

  for (int t = 0; t < 8; ++t) {
    const size_t trow0 = tok0 + t * 64;
    #pragma unroll
    for (int i = 0; i < 8; ++i) {
      int pbase = (i * 4 + wid) * 64;
      int p = pbase + lane;
      int row = p >> 5, sl = p & 31;
      gload_lds16(inh + (trow0 + row) * CDIM + (size_t)((sl ^ (row & 7)) * 8),
                  tile + pbase * 16);
    }
    __syncthreads();

    f32x4 acc[4] = {{0,0,0,0},{0,0,0,0},{0,0,0,0},{0,0,0,0}};
    #pragma unroll
    for (int kc = 0; kc < 8; ++kc) {
      half8 a = *(const half8*)(tile + (wid * 16 + lr) * 512 +
                                ((((kc << 2) | g) ^ (lr & 7)) << 4));
      #pragma unroll
      for (int jc = 0; jc < 4; ++jc) {
        half8 bf = *(const half8*)(wt + (jc * 16 + lr) * 512 +
                                   ((((kc << 2) | g) ^ (lr & 7)) << 4));
        acc[jc] = __builtin_amdgcn_mfma_f32_16x16x32_f16(a, bf, acc[jc], 0, 0, 0);
      }
    }

    if (mode == 3) {
      #pragma unroll
      for (int jc = 0; jc < 4; ++jc) {
        #pragma unroll
        for (int r = 0; r < 4; ++r) {
          size_t row = trow0 + wid * 16 + g * 4 + r;
          size_t off = row * CDIM + jstrip * 64 + jc * 16 + lr;
          outf[off] = acc[jc][r] + bjv[jc] + xnf[off];
        }
      }
    } else {
      const float csc = (mode == 0) ? 0.09016844005556021f : 1.0f; // log2(e)/16
      __syncthreads();
      _Float16* ot = (_Float16*)tile;  // [64][72]
      #pragma unroll
      for (int jc = 0; jc < 4; ++jc)
        #pragma unroll
        for (int r = 0; r < 4; ++r)
          ot[(wid * 16 + g * 4 + r) * 72 + jc * 16 + lr] =
              (_Float16)((acc[jc][r] + bjv[jc]) * csc);
      __syncthreads();
      if (mode != 2) {
        _Float16* dst = (mode == 0) ? qg : kg;
        #pragma unroll
        for (int it = 0; it < 2; ++it) {
          int s = it * 256 + tid;
          int row = s >> 3, sl = s & 7;
          half8 vv = *(const half8*)(ot + row * 72 + sl * 8);
          *(half8*)(dst + (trow0 + row) * CDIM + jstrip * 64 + sl * 8) = vv;
        }
      } else {
        #pragma unroll
        for (int it = 0; it < 2; ++it) {
          int s = it * 256 + tid;
          int j = s >> 3, ns = s & 7;
          half8 vv;
          #pragma unroll
          for (int e = 0; e < 8; ++e) vv[e] = ot[(ns * 8 + e) * 72 + j];
          size_t bb  = trow0 >> 12;
          size_t nin = (trow0 & 4095) + ns * 8;
          *(half8*)(vtg + ((size_t)bb * CDIM + jstrip * 64 + j) * NSEQ + nin) = vv;
        }
      }
    }
    __syncthreads();
  }
}

// ---------------- flash attention v7: swapped-QK^T 32x32 (R8-verified math)
// R9 deltas (perf only, math identical to R8):
//  - hoisted iteration-invariant staging pointers/LDS offsets (spill diet)
//  - P-pack in two 8-value batches (halves transient register live range)
//  - tree reductions for row-max / row-sum (VALU critical path 15 -> 4)
//  - s_setprio(1) around S and PV MFMA clusters (T5)
// LDS: K0 @0, K1 @32K, V0 @64K, V1 @96K, mbuf @128K, lbuf @129K = 133120 B.
#define ATTN_LDS 133120

__global__ __launch_bounds__(512)
__attribute__((amdgpu_waves_per_eu(2, 2)))
void attn_kernel(
    const _Float16* __restrict__ qg, const _Float16* __restrict__ kg,
    const _Float16* __restrict__ vtg, _Float16* __restrict__ og) {
  extern __shared__ char smem[];
  float* mb = (float*)(smem + 131072);  // [8 waves][32 q]
  float* lb = (float*)(smem + 132096);  // [8 waves][32 q]

  const int tid  = threadIdx.x;
  const int lane = tid & 63;
  const int wid  = tid >> 6;    // 0..7
  const int l31  = lane & 31;
  const int hi   = lane >> 5;   // 0/1
  const int qg_  = wid & 3;     // q-group (32 rows)
  const int kvh  = wid >> 2;    // kv half of each 64-tile
  const int b    = blockIdx.x & 7;        // XCD-affine batch
  const int n0   = (blockIdx.x >> 3) * 128;

  // ---- iteration-invariant staging addresses (hoisted: spill diet)
  const _Float16* ksrc[4];
  const _Float16* vsrc[4];
  uint32_t sdst[4];
  #pragma unroll
  for (int i = 0; i < 4; ++i) {
    int pbase = (i * 8 + wid) * 64;
    int p = pbase + lane;
    int row = p >> 5, sl = p & 31;
    ksrc[i] = kg + ((size_t)(b * NSEQ + row)) * CDIM + (sl ^ (row & 7)) * 8;
    int d = p >> 3, vsl = p & 7;
    vsrc[i] = vtg + ((size_t)(b * CDIM + d)) * NSEQ + (vsl ^ (d & 7)) * 8;
    sdst[i] = (uint32_t)(pbase * 16);
  }

  // ---- prologue: stage tile 0 (K + V^T) into buffer 0
  #pragma unroll
  for (int i = 0; i < 4; ++i) {
    gload_lds16(ksrc[i], smem + sdst[i]);
    gload_lds16(vsrc[i], smem + 65536 + sdst[i]);
  }

  // ---- Q fragments: B-operand of swapped MFMA. lane holds Q[q=l31][c=ks*16+hi*8+j]
  half8 qf[16];
  {
    const _Float16* qp =
        qg + ((size_t)(b * NSEQ + n0 + qg_ * 32 + l31)) * CDIM + hi * 8;
    #pragma unroll
    for (int ks = 0; ks < 16; ++ks) qf[ks] = *(const half8*)(qp + ks * 16);
  }

  f32x16 o[8];  // O[q=(r&3)+8*(r>>2)+4*hi][d=dt*32+l31], f32
  #pragma unroll
  for (int dt = 0; dt < 8; ++dt)
    #pragma unroll
    for (int r = 0; r < 16; ++r) o[dt][r] = 0.0f;
  float mrun = -1e30f, lrun = 0.0f;

  __syncthreads();  // prologue staging drained

  const int krow = kvh * 32 + l31;
  const int kxor = krow & 7;

  for (int t = 0; t < 64; ++t) {
    const int cur = t & 1;
    const char* kb = smem + cur * 32768;
    const char* vb = smem + 65536 + cur * 32768;

    // issue next tile's staging into the other buffer (drained at iter-end barrier)
    if (t < 63) {
      const size_t adv = (size_t)(t + 1) * 64;
      char* kn = smem + (cur ^ 1) * 32768;
      char* vn = smem + 65536 + (cur ^ 1) * 32768;
      #pragma unroll
      for (int i = 0; i < 4; ++i) {
        gload_lds16(ksrc[i] + adv * CDIM, kn + sdst[i]);
        gload_lds16(vsrc[i] + adv, vn + sdst[i]);
      }
    }

    // ---- S^T = K x Q^T : one 32x32 C-tile/wave (32 kv x 32 q), 16 k-steps
    f32x16 sacc;
    #pragma unroll
    for (int r = 0; r < 16; ++r) sacc[r] = 0.0f;
    const char* krowp = kb + krow * 512;
    __builtin_amdgcn_s_setprio(1);
    #pragma unroll
    for (int ks = 0; ks < 16; ++ks) {
      half8 kf = *(const half8*)(krowp + (((ks * 2 + hi) ^ kxor) << 4));
      sacc = __builtin_amdgcn_mfma_f32_32x32x16_f16(kf, qf[ks], sacc, 0, 0, 0);
    }
    __builtin_amdgcn_s_setprio(0);

    // ---- in-register online softmax (col q = l31; sacc[r] = S^T[kv=crow(r,hi)][q])
    // tree reduction (depth 4, clang fuses to v_max3)
    float ma = fmaxf(fmaxf(sacc[0], sacc[1]),  fmaxf(sacc[2], sacc[3]));
    float mbv= fmaxf(fmaxf(sacc[4], sacc[5]),  fmaxf(sacc[6], sacc[7]));
    float mc = fmaxf(fmaxf(sacc[8], sacc[9]),  fmaxf(sacc[10], sacc[11]));
    float md = fmaxf(fmaxf(sacc[12], sacc[13]),fmaxf(sacc[14], sacc[15]));
    float pm = fmaxf(fmaxf(ma, mbv), fmaxf(mc, md));
    pm = fmaxf(pm, sx32f(pm));  // full 32-kv row max for this tile

    if (!__all(pm - mrun <= 8.0f)) {   // defer-max (T13), THR=8 in log2 domain
      float mnew = fmaxf(mrun, pm);
      float al = exp2f(mrun - mnew);
      mrun = mnew;
      lrun *= al;
      #pragma unroll
      for (int r = 0; r < 16; ++r) {
        float ar = __shfl(al, (r & 3) + 8 * (r >> 2) + 4 * hi, 64);
        #pragma unroll
        for (int dt = 0; dt < 8; ++dt) o[dt][r] *= ar;
      }
    }

    float p[16];
    #pragma unroll
    for (int r = 0; r < 16; ++r) p[r] = exp2f(sacc[r] - mrun);
    // sum tree
    float s0 = (p[0] + p[1]) + (p[2] + p[3]);
    float s1 = (p[4] + p[5]) + (p[6] + p[7]);
    float s2 = (p[8] + p[9]) + (p[10] + p[11]);
    float s3 = (p[12] + p[13]) + (p[14] + p[15]);
    float ls = (s0 + s1) + (s2 + s3);
    lrun += ls + sx32f(ls);

    // ---- pack P -> f16 A-frags in two batches (halved transient live range)
    half8 pa0, pa1;
    {
      uint32_t c0 = pkrtz(p[0], p[1]), c1 = pkrtz(p[2], p[3]);
      uint32_t c2 = pkrtz(p[4], p[5]), c3 = pkrtz(p[6], p[7]);
      uint32_t t0 = sx32u(c0), t1 = sx32u(c1), t2 = sx32u(c2), t3 = sx32u(c3);
      pa0 = __builtin_bit_cast(half8, (u32x4){
          hi ? t2 : c0, hi ? t3 : c1, hi ? c2 : t0, hi ? c3 : t1});
    }
    {
      uint32_t c0 = pkrtz(p[8], p[9]),  c1 = pkrtz(p[10], p[11]);
      uint32_t c2 = pkrtz(p[12], p[13]), c3 = pkrtz(p[14], p[15]);
      uint32_t t0 = sx32u(c0), t1 = sx32u(c1), t2 = sx32u(c2), t3 = sx32u(c3);
      pa1 = __builtin_bit_cast(half8, (u32x4){
          hi ? t2 : c0, hi ? t3 : c1, hi ? c2 : t0, hi ? c3 : t1});
    }

    // ---- PV: O[32q x 256d] += P[32q x 32kv] x V[32kv x 256d]
    __builtin_amdgcn_s_setprio(1);
    #pragma unroll
    for (int dt = 0; dt < 8; ++dt) {
      const char* vrow = vb + (dt * 32 + l31) * 128;
      const int vx = (dt * 32 + l31) & 7;
      half8 vf0 = *(const half8*)(vrow + (((kvh * 4 + 0 + hi) ^ vx) << 4));
      half8 vf1 = *(const half8*)(vrow + (((kvh * 4 + 2 + hi) ^ vx) << 4));
      o[dt] = __builtin_amdgcn_mfma_f32_32x32x16_f16(pa0, vf0, o[dt], 0, 0, 0);
      o[dt] = __builtin_amdgcn_mfma_f32_32x32x16_f16(pa1, vf1, o[dt], 0, 0, 0);
    }
    __builtin_amdgcn_s_setprio(0);

    __syncthreads();  // reads of buf[cur] done + staging into buf[cur^1] drained
  }

  // ---- epilogue: merge the two kv-half waves (wid, wid^4) via LDS
  if (lane < 32) mb[wid * 32 + lane] = mrun;
  __syncthreads();
  float mo = mb[(wid ^ 4) * 32 + l31];
  float M  = fmaxf(mrun, mo);
  float asel = exp2f(mrun - M);   // per-lane: factor for q = l31
  if (lane < 32) lb[wid * 32 + lane] = lrun * asel;
  __syncthreads();
  float lt = lrun * asel + lb[(wid ^ 4) * 32 + l31];
  float rlt = 1.0f / lt;          // per-lane: 1/l for q = l31

  float* ob = (float*)smem + (size_t)(wid & 3) * 8192;  // [32 q][256 d] f32 per pair
  if (wid >= 4) {
    #pragma unroll
    for (int r = 0; r < 16; ++r) {
      int q = (r & 3) + 8 * (r >> 2) + 4 * hi;
      float aq = __shfl(asel, q, 64);          // factor for row q, not l31
      #pragma unroll
      for (int dt = 0; dt < 8; ++dt)
        ob[q * 256 + dt * 32 + l31] = o[dt][r] * aq;
    }
  }
  __syncthreads();
  if (wid < 4) {
    #pragma unroll
    for (int r = 0; r < 16; ++r) {
      int q = (r & 3) + 8 * (r >> 2) + 4 * hi;
      float aq = __shfl(asel, q, 64);          // factor for row q
      float rq = __shfl(rlt, q, 64);
      #pragma unroll
      for (int dt = 0; dt < 8; ++dt) {
        float v = o[dt][r] * aq + ob[q * 256 + dt * 32 + l31];
        og[((size_t)(b * NSEQ + n0 + qg_ * 32 + q)) * CDIM + dt * 32 + l31] =
            (_Float16)(v * rq);
      }
    }
  }
}

// ---------------- launcher
extern "C" void kernel_launch(void* const* d_in, const int* in_sizes, int n_in,
                              void* d_out, int out_size, void* d_ws, size_t ws_size,
                              hipStream_t stream) {
  const float* x   = (const float*)d_in[0];
  const float* gam = (const float*)d_in[1];
  const float* bet = (const float*)d_in[2];
  const float* wq  = (const float*)d_in[3];
  const float* bq  = (const float*)d_in[4];
  const float* wk  = (const float*)d_in[5];
  const float* bk  = (const float*)d_in[6];
  const float* wv  = (const float*)d_in[7];
  const float* bv  = (const float*)d_in[8];
  const float* wp  = (const float*)d_in[9];
  const float* bp  = (const float*)d_in[10];
  float* out = (float*)d_out;

  char* ws = (char*)d_ws;
  float*    xnf = (float*)ws;                             // 32MB fp32 xn (residual)
  _Float16* xnh = (_Float16*)(ws + (32u << 20));          // 16MB f16 xn
  _Float16* qh  = (_Float16*)(ws + (48u << 20));          // 16MB q (scaled)
  _Float16* kh  = (_Float16*)(ws + (64u << 20));          // 16MB k
  _Float16* vth = (_Float16*)(ws + (80u << 20));          // 16MB v^T [b][c][n]
  _Float16* oh  = (_Float16*)(ws + (96u << 20));          // 16MB attn out

  (void)hipFuncSetAttribute((const void*)proj_kernel,
                            hipFuncAttributeMaxDynamicSharedMemorySize, 65536);
  (void)hipFuncSetAttribute((const void*)attn_kernel,
                            hipFuncAttributeMaxDynamicSharedMemorySize, ATTN_LDS);

  ln_kernel<<<NTOK / 4, 256, 0, stream>>>(x, gam, bet, xnf, xnh);
  proj_kernel<<<dim3(64, 4, 3), 256, 65536, stream>>>(
      xnh, wq, bq, wk, bk, wv, bv, wp, bp, qh, kh, vth, xnf, out, 0);
  attn_kernel<<<256, 512, ATTN_LDS, stream>>>(qh, kh, vth, oh);
  proj_kernel<<<dim3(64, 4, 1), 256, 65536, stream>>>(
      oh, wq, bq, wk, bk, wv, bv, wp, bp, qh, kh, vth, xnf, out, 3);
}

// Round 10
// 298.935 us; speedup vs baseline: 1.0733x; 1.0733x over previous
//
#include <hip/hip_runtime.h>
#include <cstdint>

#define NB    8
#define NSEQ  4096
#define CDIM  256
#define NTOK  (NB*NSEQ)

typedef _Float16 half8  __attribute__((ext_vector_type(8)));
typedef _Float16 half4v __attribute__((ext_vector_type(4)));
typedef float    f32x4  __attribute__((ext_vector_type(4)));
typedef float    f32x16 __attribute__((ext_vector_type(16)));
typedef uint32_t u32x4  __attribute__((ext_vector_type(4)));

typedef unsigned int u32_g __attribute__((address_space(1)));
typedef unsigned int u32_l __attribute__((address_space(3)));

// direct global->LDS, 16B per lane; LDS dest = wave-uniform base + lane*16
__device__ __forceinline__ void gload_lds16(const void* g, void* l) {
  __builtin_amdgcn_global_load_lds((u32_g*)(uintptr_t)g,
                                   (u32_l*)(uint32_t)(uintptr_t)l, 16, 0, 0);
}

__device__ __forceinline__ uint32_t pkrtz(float a, float b) {
  auto h = __builtin_amdgcn_cvt_pkrtz(a, b);  // lo16 = a, hi16 = b
  return __builtin_bit_cast(uint32_t, h);
}
// lane^32 exchange via shfl (semantics-certain)
__device__ __forceinline__ float sx32f(float v) { return __shfl_xor(v, 32, 64); }
__device__ __forceinline__ uint32_t sx32u(uint32_t v) {
  return (uint32_t)__shfl_xor((int)v, 32, 64);
}

// ---------------- LayerNorm: one wave per token (C=256 = 64 lanes x float4)
__global__ __launch_bounds__(256) void ln_kernel(
    const float* __restrict__ x, const float* __restrict__ gam,
    const float* __restrict__ bet, float* __restrict__ xnf,
    _Float16* __restrict__ xnh) {
  const int lane = threadIdx.x & 63;
  const size_t tok = (size_t)blockIdx.x * 4 + (threadIdx.x >> 6);
  const float4 v = ((const float4*)(x + tok * CDIM))[lane];
  float s  = v.x + v.y + v.z + v.w;
  float s2 = v.x*v.x + v.y*v.y + v.z*v.z + v.w*v.w;
  #pragma unroll
  for (int m = 1; m < 64; m <<= 1) {
    s  += __shfl_xor(s,  m, 64);
    s2 += __shfl_xor(s2, m, 64);
  }
  const float mean = s * (1.0f / CDIM);
  const float rstd = rsqrtf(s2 * (1.0f / CDIM) - mean * mean + 1e-3f);
  const float4 gv = ((const float4*)gam)[lane];
  const float4 bv = ((const float4*)bet)[lane];
  float4 o;
  o.x = (v.x - mean) * rstd * gv.x + bv.x;
  o.y = (v.y - mean) * rstd * gv.y + bv.y;
  o.z = (v.z - mean) * rstd * gv.z + bv.z;
  o.w = (v.w - mean) * rstd * gv.w + bv.w;
  ((float4*)(xnf + tok * CDIM))[lane] = o;
  half4v h;
  h[0] = (_Float16)o.x; h[1] = (_Float16)o.y;
  h[2] = (_Float16)o.z; h[3] = (_Float16)o.w;
  ((half4v*)(xnh + tok * CDIM))[lane] = h;
}

// ---------------- projection GEMM (unchanged from R1)
__global__ __launch_bounds__(256, 2) void proj_kernel(
    const _Float16* __restrict__ inh,
    const float* __restrict__ wq_, const float* __restrict__ bq_,
    const float* __restrict__ wk_, const float* __restrict__ bk_,
    const float* __restrict__ wv_, const float* __restrict__ bv_,
    const float* __restrict__ wp_, const float* __restrict__ bp_,
    _Float16* __restrict__ qg, _Float16* __restrict__ kg, _Float16* __restrict__ vtg,
    const float* __restrict__ xnf, float* __restrict__ outf,
    int mode_base) {
  extern __shared__ char smem[];
  const int mode = mode_base + blockIdx.z;
  const float* wsel = (mode == 0) ? wq_ : (mode == 1) ? wk_ : (mode == 2) ? wv_ : wp_;
  const float* bsel = (mode == 0) ? bq_ : (mode == 1) ? bk_ : (mode == 2) ? bv_ : bp_;

  const int tid = threadIdx.x;
  const int lane = tid & 63;
  const int wid  = tid >> 6;     // 0..3
  const int g    = lane >> 4;    // 0..3
  const int lr   = lane & 15;
  const int jstrip = blockIdx.y; // 0..3
  const size_t tok0 = (size_t)blockIdx.x * 512;

  char* wt   = smem;             // [64 j][256 c] f16, XOR-swizzled (32KB)
  char* tile = smem + 32768;     // [64 tok][256 c] f16, swizzled (32KB)

  for (int i = 0; i < 64; ++i) {
    int idx = i * 256 + tid;
    int c = idx >> 6, j = idx & 63;
    float val = wsel[(size_t)c * CDIM + jstrip * 64 + j];
    *(_Float16*)(wt + j * 512 + ((((c >> 3) ^ (j & 7))) << 4) + ((c & 7) << 1)) =
        (_Float16)val;
  }
  float bjv[4];
  #pragma unroll
  for (int jc = 0; jc < 4; ++jc) bjv[jc] = bsel[jstrip * 64 + jc * 16 + lr];
  __syncthreads();

  for (int t = 0; t < 8; ++t) {
    const size_t trow0 = tok0 + t * 64;
    #pragma unroll
    for (int i = 0; i < 8; ++i) {
      int pbase = (i * 4 + wid) * 64;
      int p = pbase + lane;
      int row = p >> 5, sl = p & 31;
      gload_lds16(inh + (trow0 + row) * CDIM + (size_t)((sl ^ (row & 7)) * 8),
                  tile + pbase * 16);
    }
    __syncthreads();

    f32x4 acc[4] = {{0,0,0,0},{0,0,0,0},{0,0,0,0},{0,0,0,0}};
    #pragma unroll
    for (int kc = 0; kc < 8; ++kc) {
      half8 a = *(const half8*)(tile + (wid * 16 + lr) * 512 +
                                ((((kc << 2) | g) ^ (lr & 7)) << 4));
      #pragma unroll
      for (int jc = 0; jc < 4; ++jc) {
        half8 bf = *(const half8*)(wt + (jc * 16 + lr) * 512 +
                                   ((((kc << 2) | g) ^ (lr & 7)) << 4));
        acc[jc] = __builtin_amdgcn_mfma_f32_16x16x32_f16(a, bf, acc[jc], 0, 0, 0);
      }
    }

    if (mode == 3) {
      #pragma unroll
      for (int jc = 0; jc < 4; ++jc) {
        #pragma unroll
        for (int r = 0; r < 4; ++r) {
          size_t row = trow0 + wid * 16 + g * 4 + r;
          size_t off = row * CDIM + jstrip * 64 + jc * 16 + lr;
          outf[off] = acc[jc][r] + bjv[jc] + xnf[off];
        }
      }
    } else {
      const float csc = (mode == 0) ? 0.09016844005556021f : 1.0f; // log2(e)/16
      __syncthreads();
      _Float16* ot = (_Float16*)tile;  // [64][72]
      #pragma unroll
      for (int jc = 0; jc < 4; ++jc)
        #pragma unroll
        for (int r = 0; r < 4; ++r)
          ot[(wid * 16 + g * 4 + r) * 72 + jc * 16 + lr] =
              (_Float16)((acc[jc][r] + bjv[jc]) * csc);
      __syncthreads();
      if (mode != 2) {
        _Float16* dst = (mode == 0) ? qg : kg;
        #pragma unroll
        for (int it = 0; it < 2; ++it) {
          int s = it * 256 + tid;
          int row = s >> 3, sl = s & 7;
          half8 vv = *(const half8*)(ot + row * 72 + sl * 8);
          *(half8*)(dst + (trow0 + row) * CDIM + jstrip * 64 + sl * 8) = vv;
        }
      } else {
        #pragma unroll
        for (int it = 0; it < 2; ++it) {
          int s = it * 256 + tid;
          int j = s >> 3, ns = s & 7;
          half8 vv;
          #pragma unroll
          for (int e = 0; e < 8; ++e) vv[e] = ot[(ns * 8 + e) * 72 + j];
          size_t bb  = trow0 >> 12;
          size_t nin = (trow0 & 4095) + ns * 8;
          *(half8*)(vtg + ((size_t)bb * CDIM + jstrip * 64 + j) * NSEQ + nin) = vv;
        }
      }
    }
    __syncthreads();
  }
}

// ---------------- flash attention v8: R8-exact base + dual S-accumulator
// R9 (setprio + hoisted ptrs + tree reductions) regressed 226->265us and is
// fully reverted. Single R10 change: the S-phase was 16 MFMAs serialized
// through ONE accumulator (16 x ~30cyc latency ~ 500 cyc/wave/iter serial;
// MfmaUtil stuck at 26%). Split into two independent 8-deep chains
// (even/odd k-steps, interleaved issue) + one f32x16 add at the end.
// LDS: K0 @0, K1 @32K, V0 @64K, V1 @96K, mbuf @128K, lbuf @129K = 133120 B.
#define ATTN_LDS 133120

__global__ __launch_bounds__(512)
__attribute__((amdgpu_waves_per_eu(2, 2)))
void attn_kernel(
    const _Float16* __restrict__ qg, const _Float16* __restrict__ kg,
    const _Float16* __restrict__ vtg, _Float16* __restrict__ og) {
  extern __shared__ char smem[];
  float* mb = (float*)(smem + 131072);  // [8 waves][32 q]
  float* lb = (float*)(smem + 132096);  // [8 waves][32 q]

  const int tid  = threadIdx.x;
  const int lane = tid & 63;
  const int wid  = tid >> 6;    // 0..7
  const int l31  = lane & 31;
  const int hi   = lane >> 5;   // 0/1
  const int qg_  = wid & 3;     // q-group (32 rows)
  const int kvh  = wid >> 2;    // kv half of each 64-tile
  const int b    = blockIdx.x & 7;        // XCD-affine batch
  const int n0   = (blockIdx.x >> 3) * 128;

  // ---- prologue: stage tile 0 (K + V^T) into buffer 0
  #pragma unroll
  for (int i = 0; i < 4; ++i) {
    int pbase = (i * 8 + wid) * 64;
    int p = pbase + lane;
    int row = p >> 5, sl = p & 31;
    gload_lds16(kg + ((size_t)(b * NSEQ + row)) * CDIM + (sl ^ (row & 7)) * 8,
                smem + pbase * 16);
    int d = p >> 3, vsl = p & 7;
    gload_lds16(vtg + ((size_t)(b * CDIM + d)) * NSEQ + (vsl ^ (d & 7)) * 8,
                smem + 65536 + pbase * 16);
  }

  // ---- Q fragments: B-operand of swapped MFMA. lane holds Q[q=l31][c=ks*16+hi*8+j]
  half8 qf[16];
  {
    const _Float16* qp =
        qg + ((size_t)(b * NSEQ + n0 + qg_ * 32 + l31)) * CDIM + hi * 8;
    #pragma unroll
    for (int ks = 0; ks < 16; ++ks) qf[ks] = *(const half8*)(qp + ks * 16);
  }

  f32x16 o[8];  // O[q=(r&3)+8*(r>>2)+4*hi][d=dt*32+l31], f32
  #pragma unroll
  for (int dt = 0; dt < 8; ++dt)
    #pragma unroll
    for (int r = 0; r < 16; ++r) o[dt][r] = 0.0f;
  float mrun = -1e30f, lrun = 0.0f;

  __syncthreads();  // prologue staging drained

  const int krow = kvh * 32 + l31;
  const int kxor = krow & 7;

  for (int t = 0; t < 64; ++t) {
    const int cur = t & 1;
    const char* kb = smem + cur * 32768;
    const char* vb = smem + 65536 + cur * 32768;

    // issue next tile's staging into the other buffer (drained at iter-end barrier)
    if (t < 63) {
      const int kv0n = (t + 1) * 64;
      char* kn = smem + (cur ^ 1) * 32768;
      char* vn = smem + 65536 + (cur ^ 1) * 32768;
      #pragma unroll
      for (int i = 0; i < 4; ++i) {
        int pbase = (i * 8 + wid) * 64;
        int p = pbase + lane;
        int row = p >> 5, sl = p & 31;
        gload_lds16(kg + ((size_t)(b * NSEQ + kv0n + row)) * CDIM + (sl ^ (row & 7)) * 8,
                    kn + pbase * 16);
        int d = p >> 3, vsl = p & 7;
        gload_lds16(vtg + ((size_t)(b * CDIM + d)) * NSEQ + kv0n + (vsl ^ (d & 7)) * 8,
                    vn + pbase * 16);
      }
    }

    // ---- S^T = K x Q^T : 32x32 tile, TWO independent 8-deep MFMA chains
    f32x16 sa, sb;
    #pragma unroll
    for (int r = 0; r < 16; ++r) { sa[r] = 0.0f; sb[r] = 0.0f; }
    const char* krowp = kb + krow * 512;
    #pragma unroll
    for (int ks = 0; ks < 8; ++ks) {
      half8 kfa = *(const half8*)(krowp + ((((2 * ks) * 2 + hi) ^ kxor) << 4));
      half8 kfb = *(const half8*)(krowp + ((((2 * ks + 1) * 2 + hi) ^ kxor) << 4));
      sa = __builtin_amdgcn_mfma_f32_32x32x16_f16(kfa, qf[2 * ks], sa, 0, 0, 0);
      sb = __builtin_amdgcn_mfma_f32_32x32x16_f16(kfb, qf[2 * ks + 1], sb, 0, 0, 0);
    }
    f32x16 sacc = sa + sb;  // fp32 elementwise combine (tolerance is loose)

    // ---- in-register online softmax (col q = l31; sacc[r] = S^T[kv=crow(r,hi)][q])
    float pm = sacc[0];
    #pragma unroll
    for (int r = 1; r < 16; ++r) pm = fmaxf(pm, sacc[r]);
    pm = fmaxf(pm, sx32f(pm));  // full 32-kv row max for this tile

    if (!__all(pm - mrun <= 8.0f)) {   // defer-max (T13), THR=8 in log2 domain
      float mnew = fmaxf(mrun, pm);
      float al = exp2f(mrun - mnew);
      mrun = mnew;
      lrun *= al;
      #pragma unroll
      for (int r = 0; r < 16; ++r) {
        float ar = __shfl(al, (r & 3) + 8 * (r >> 2) + 4 * hi, 64);
        #pragma unroll
        for (int dt = 0; dt < 8; ++dt) o[dt][r] *= ar;
      }
    }

    float p[16], ls = 0.0f;
    #pragma unroll
    for (int r = 0; r < 16; ++r) { p[r] = exp2f(sacc[r] - mrun); ls += p[r]; }
    lrun += ls + sx32f(ls);

    // ---- pack P -> f16 A-frags: cvt_pkrtz + lane^32 shfl + select
    uint32_t c01 = pkrtz(p[0],  p[1]),  c23 = pkrtz(p[2],  p[3]);
    uint32_t c45 = pkrtz(p[4],  p[5]),  c67 = pkrtz(p[6],  p[7]);
    uint32_t c89 = pkrtz(p[8],  p[9]),  cab = pkrtz(p[10], p[11]);
    uint32_t ccd = pkrtz(p[12], p[13]), cef = pkrtz(p[14], p[15]);
    uint32_t t01 = sx32u(c01), t23 = sx32u(c23);
    uint32_t t45 = sx32u(c45), t67 = sx32u(c67);
    uint32_t t89 = sx32u(c89), tab = sx32u(cab);
    uint32_t tcd = sx32u(ccd), tef = sx32u(cef);
    half8 pa0 = __builtin_bit_cast(half8, (u32x4){
        hi ? t45 : c01, hi ? t67 : c23, hi ? c45 : t01, hi ? c67 : t23});
    half8 pa1 = __builtin_bit_cast(half8, (u32x4){
        hi ? tcd : c89, hi ? tef : cab, hi ? ccd : t89, hi ? cef : tab});

    // ---- PV: O[32q x 256d] += P[32q x 32kv] x V[32kv x 256d]
    #pragma unroll
    for (int dt = 0; dt < 8; ++dt) {
      const char* vrow = vb + (dt * 32 + l31) * 128;
      const int vx = (dt * 32 + l31) & 7;
      half8 vf0 = *(const half8*)(vrow + (((kvh * 4 + 0 + hi) ^ vx) << 4));
      half8 vf1 = *(const half8*)(vrow + (((kvh * 4 + 2 + hi) ^ vx) << 4));
      o[dt] = __builtin_amdgcn_mfma_f32_32x32x16_f16(pa0, vf0, o[dt], 0, 0, 0);
      o[dt] = __builtin_amdgcn_mfma_f32_32x32x16_f16(pa1, vf1, o[dt], 0, 0, 0);
    }

    __syncthreads();  // reads of buf[cur] done + staging into buf[cur^1] drained
  }

  // ---- epilogue: merge the two kv-half waves (wid, wid^4) via LDS
  if (lane < 32) mb[wid * 32 + lane] = mrun;
  __syncthreads();
  float mo = mb[(wid ^ 4) * 32 + l31];
  float M  = fmaxf(mrun, mo);
  float asel = exp2f(mrun - M);   // per-lane: factor for q = l31
  if (lane < 32) lb[wid * 32 + lane] = lrun * asel;
  __syncthreads();
  float lt = lrun * asel + lb[(wid ^ 4) * 32 + l31];
  float rlt = 1.0f / lt;          // per-lane: 1/l for q = l31

  float* ob = (float*)smem + (size_t)(wid & 3) * 8192;  // [32 q][256 d] f32 per pair
  if (wid >= 4) {
    #pragma unroll
    for (int r = 0; r < 16; ++r) {
      int q = (r & 3) + 8 * (r >> 2) + 4 * hi;
      float aq = __shfl(asel, q, 64);          // factor for row q, not l31
      #pragma unroll
      for (int dt = 0; dt < 8; ++dt)
        ob[q * 256 + dt * 32 + l31] = o[dt][r] * aq;
    }
  }
  __syncthreads();
  if (wid < 4) {
    #pragma unroll
    for (int r = 0; r < 16; ++r) {
      int q = (r & 3) + 8 * (r >> 2) + 4 * hi;
      float aq = __shfl(asel, q, 64);          // factor for row q
      float rq = __shfl(rlt, q, 64);
      #pragma unroll
      for (int dt = 0; dt < 8; ++dt) {
        float v = o[dt][r] * aq + ob[q * 256 + dt * 32 + l31];
        og[((size_t)(b * NSEQ + n0 + qg_ * 32 + q)) * CDIM + dt * 32 + l31] =
            (_Float16)(v * rq);
      }
    }
  }
}

// ---------------- launcher
extern "C" void kernel_launch(void* const* d_in, const int* in_sizes, int n_in,
                              void* d_out, int out_size, void* d_ws, size_t ws_size,
                              hipStream_t stream) {
  const float* x   = (const float*)d_in[0];
  const float* gam = (const float*)d_in[1];
  const float* bet = (const float*)d_in[2];
  const float* wq  = (const float*)d_in[3];
  const float* bq  = (const float*)d_in[4];
  const float* wk  = (const float*)d_in[5];
  const float* bk  = (const float*)d_in[6];
  const float* wv  = (const float*)d_in[7];
  const float* bv  = (const float*)d_in[8];
  const float* wp  = (const float*)d_in[9];
  const float* bp  = (const float*)d_in[10];
  float* out = (float*)d_out;

  char* ws = (char*)d_ws;
  float*    xnf = (float*)ws;                             // 32MB fp32 xn (residual)
  _Float16* xnh = (_Float16*)(ws + (32u << 20));          // 16MB f16 xn
  _Float16* qh  = (_Float16*)(ws + (48u << 20));          // 16MB q (scaled)
  _Float16* kh  = (_Float16*)(ws + (64u << 20));          // 16MB k
  _Float16* vth = (_Float16*)(ws + (80u << 20));          // 16MB v^T [b][c][n]
  _Float16* oh  = (_Float16*)(ws + (96u << 20));          // 16MB attn out

  (void)hipFuncSetAttribute((const void*)proj_kernel,
                            hipFuncAttributeMaxDynamicSharedMemorySize, 65536);
  (void)hipFuncSetAttribute((const void*)attn_kernel,
                            hipFuncAttributeMaxDynamicSharedMemorySize, ATTN_LDS);

  ln_kernel<<<NTOK / 4, 256, 0, stream>>>(x, gam, bet, xnf, xnh);
  proj_kernel<<<dim3(64, 4, 3), 256, 65536, stream>>>(
      xnh, wq, bq, wk, bk, wv, bv, wp, bp, qh, kh, vth, xnf, out, 0);
  attn_kernel<<<256, 512, ATTN_LDS, stream>>>(qh, kh, vth, oh);
  proj_kernel<<<dim3(64, 4, 1), 256, 65536, stream>>>(
      oh, wq, bq, wk, bk, wv, bv, wp, bp, qh, kh, vth, xnf, out, 3);
}

// Round 11
// 276.652 us; speedup vs baseline: 1.1598x; 1.0805x over previous
//
#include <hip/hip_runtime.h>
#include <cstdint>

#define NB    8
#define NSEQ  4096
#define CDIM  256
#define NTOK  (NB*NSEQ)

typedef _Float16 half8  __attribute__((ext_vector_type(8)));
typedef _Float16 half4v __attribute__((ext_vector_type(4)));
typedef float    f32x4  __attribute__((ext_vector_type(4)));
typedef float    f32x16 __attribute__((ext_vector_type(16)));
typedef uint32_t u32x4  __attribute__((ext_vector_type(4)));

typedef unsigned int u32_g __attribute__((address_space(1)));
typedef unsigned int u32_l __attribute__((address_space(3)));

// direct global->LDS, 16B per lane; LDS dest = wave-uniform base + lane*16
__device__ __forceinline__ void gload_lds16(const void* g, void* l) {
  __builtin_amdgcn_global_load_lds((u32_g*)(uintptr_t)g,
                                   (u32_l*)(uint32_t)(uintptr_t)l, 16, 0, 0);
}

__device__ __forceinline__ uint32_t pkrtz(float a, float b) {
  auto h = __builtin_amdgcn_cvt_pkrtz(a, b);  // lo16 = a, hi16 = b
  return __builtin_bit_cast(uint32_t, h);
}
// lane^32 exchange via shfl (semantics-certain)
__device__ __forceinline__ float sx32f(float v) { return __shfl_xor(v, 32, 64); }
__device__ __forceinline__ uint32_t sx32u(uint32_t v) {
  return (uint32_t)__shfl_xor((int)v, 32, 64);
}

// ---------------- LayerNorm: one wave per token (C=256 = 64 lanes x float4)
__global__ __launch_bounds__(256) void ln_kernel(
    const float* __restrict__ x, const float* __restrict__ gam,
    const float* __restrict__ bet, float* __restrict__ xnf,
    _Float16* __restrict__ xnh) {
  const int lane = threadIdx.x & 63;
  const size_t tok = (size_t)blockIdx.x * 4 + (threadIdx.x >> 6);
  const float4 v = ((const float4*)(x + tok * CDIM))[lane];
  float s  = v.x + v.y + v.z + v.w;
  float s2 = v.x*v.x + v.y*v.y + v.z*v.z + v.w*v.w;
  #pragma unroll
  for (int m = 1; m < 64; m <<= 1) {
    s  += __shfl_xor(s,  m, 64);
    s2 += __shfl_xor(s2, m, 64);
  }
  const float mean = s * (1.0f / CDIM);
  const float rstd = rsqrtf(s2 * (1.0f / CDIM) - mean * mean + 1e-3f);
  const float4 gv = ((const float4*)gam)[lane];
  const float4 bv = ((const float4*)bet)[lane];
  float4 o;
  o.x = (v.x - mean) * rstd * gv.x + bv.x;
  o.y = (v.y - mean) * rstd * gv.y + bv.y;
  o.z = (v.z - mean) * rstd * gv.z + bv.z;
  o.w = (v.w - mean) * rstd * gv.w + bv.w;
  ((float4*)(xnf + tok * CDIM))[lane] = o;
  half4v h;
  h[0] = (_Float16)o.x; h[1] = (_Float16)o.y;
  h[2] = (_Float16)o.z; h[3] = (_Float16)o.w;
  ((half4v*)(xnh + tok * CDIM))[lane] = h;
}

// ---------------- projection GEMM (unchanged from R1)
__global__ __launch_bounds__(256, 2) void proj_kernel(
    const _Float16* __restrict__ inh,
    const float* __restrict__ wq_, const float* __restrict__ bq_,
    const float* __restrict__ wk_, const float* __restrict__ bk_,
    const float* __restrict__ wv_, const float* __restrict__ bv_,
    const float* __restrict__ wp_, const float* __restrict__ bp_,
    _Float16* __restrict__ qg, _Float16* __restrict__ kg, _Float16* __restrict__ vtg,
    const float* __restrict__ xnf, float* __restrict__ outf,
    int mode_base) {
  extern __shared__ char smem[];
  const int mode = mode_base + blockIdx.z;
  const float* wsel = (mode == 0) ? wq_ : (mode == 1) ? wk_ : (mode == 2) ? wv_ : wp_;
  const float* bsel = (mode == 0) ? bq_ : (mode == 1) ? bk_ : (mode == 2) ? bv_ : bp_;

  const int tid = threadIdx.x;
  const int lane = tid & 63;
  const int wid  = tid >> 6;     // 0..3
  const int g    = lane >> 4;    // 0..3
  const int lr   = lane & 15;
  const int jstrip = blockIdx.y; // 0..3
  const size_t tok0 = (size_t)blockIdx.x * 512;

  char* wt   = smem;             // [64 j][256 c] f16, XOR-swizzled (32KB)
  char* tile = smem + 32768;     // [64 tok][256 c] f16, swizzled (32KB)

  for (int i = 0; i < 64; ++i) {
    int idx = i * 256 + tid;
    int c = idx >> 6, j = idx & 63;
    float val = wsel[(size_t)c * CDIM + jstrip * 64 + j];
    *(_Float16*)(wt + j * 512 + ((((c >> 3) ^ (j & 7))) << 4) + ((c & 7) << 1)) =
        (_Float16)val;
  }
  float bjv[4];
  #pragma unroll
  for (int jc = 0; jc < 4; ++jc) bjv[jc] = bsel[jstrip * 64 + jc * 16 + lr];
  __syncthreads();

  for (int t = 0; t < 8; ++t) {
    const size_t trow0 = tok0 + t * 64;
    #pragma unroll
    for (int i = 0; i < 8; ++i) {
      int pbase = (i * 4 + wid) * 64;
      int p = pbase + lane;
      int row = p >> 5, sl = p & 31;
      gload_lds16(inh + (trow0 + row) * CDIM + (size_t)((sl ^ (row & 7)) * 8),
                  tile + pbase * 16);
    }
    __syncthreads();

    f32x4 acc[4] = {{0,0,0,0},{0,0,0,0},{0,0,0,0},{0,0,0,0}};
    #pragma unroll
    for (int kc = 0; kc < 8; ++kc) {
      half8 a = *(const half8*)(tile + (wid * 16 + lr) * 512 +
                                ((((kc << 2) | g) ^ (lr & 7)) << 4));
      #pragma unroll
      for (int jc = 0; jc < 4; ++jc) {
        half8 bf = *(const half8*)(wt + (jc * 16 + lr) * 512 +
                                   ((((kc << 2) | g) ^ (lr & 7)) << 4));
        acc[jc] = __builtin_amdgcn_mfma_f32_16x16x32_f16(a, bf, acc[jc], 0, 0, 0);
      }
    }

    if (mode == 3) {
      #pragma unroll
      for (int jc = 0; jc < 4; ++jc) {
        #pragma unroll
        for (int r = 0; r < 4; ++r) {
          size_t row = trow0 + wid * 16 + g * 4 + r;
          size_t off = row * CDIM + jstrip * 64 + jc * 16 + lr;
          outf[off] = acc[jc][r] + bjv[jc] + xnf[off];
        }
      }
    } else {
      const float csc = (mode == 0) ? 0.09016844005556021f : 1.0f; // log2(e)/16
      __syncthreads();
      _Float16* ot = (_Float16*)tile;  // [64][72]
      #pragma unroll
      for (int jc = 0; jc < 4; ++jc)
        #pragma unroll
        for (int r = 0; r < 4; ++r)
          ot[(wid * 16 + g * 4 + r) * 72 + jc * 16 + lr] =
              (_Float16)((acc[jc][r] + bjv[jc]) * csc);
      __syncthreads();
      if (mode != 2) {
        _Float16* dst = (mode == 0) ? qg : kg;
        #pragma unroll
        for (int it = 0; it < 2; ++it) {
          int s = it * 256 + tid;
          int row = s >> 3, sl = s & 7;
          half8 vv = *(const half8*)(ot + row * 72 + sl * 8);
          *(half8*)(dst + (trow0 + row) * CDIM + jstrip * 64 + sl * 8) = vv;
        }
      } else {
        #pragma unroll
        for (int it = 0; it < 2; ++it) {
          int s = it * 256 + tid;
          int j = s >> 3, ns = s & 7;
          half8 vv;
          #pragma unroll
          for (int e = 0; e < 8; ++e) vv[e] = ot[(ns * 8 + e) * 72 + j];
          size_t bb  = trow0 >> 12;
          size_t nin = (trow0 & 4095) + ns * 8;
          *(half8*)(vtg + ((size_t)bb * CDIM + jstrip * 64 + j) * NSEQ + nin) = vv;
        }
      }
    }
    __syncthreads();
  }
}

// ---------------- flash attention v9: R8-exact schedule + register diet
// R9 (setprio bundle) and R10 (dual S-chain) both regressed via spill: the
// live set sits ON the 256-reg/wave cliff (o[8]=128 AGPR + qf=64 VGPR), so
// any +16 regs converts to in-loop scratch (WRITE_SIZE 36.9->40.4MB).
// R11 changes ONLY register pressure, zero math/schedule changes vs R8:
//  - exp2 in place into sacc (removes separate p[16]: -16 live)
//  - P-pack in two 8-value batches (pack temps 16 -> 8: -8 live)
// LDS: K0 @0, K1 @32K, V0 @64K, V1 @96K, mbuf @128K, lbuf @129K = 133120 B.
#define ATTN_LDS 133120

__global__ __launch_bounds__(512)
__attribute__((amdgpu_waves_per_eu(2, 2)))
void attn_kernel(
    const _Float16* __restrict__ qg, const _Float16* __restrict__ kg,
    const _Float16* __restrict__ vtg, _Float16* __restrict__ og) {
  extern __shared__ char smem[];
  float* mb = (float*)(smem + 131072);  // [8 waves][32 q]
  float* lb = (float*)(smem + 132096);  // [8 waves][32 q]

  const int tid  = threadIdx.x;
  const int lane = tid & 63;
  const int wid  = tid >> 6;    // 0..7
  const int l31  = lane & 31;
  const int hi   = lane >> 5;   // 0/1
  const int qg_  = wid & 3;     // q-group (32 rows)
  const int kvh  = wid >> 2;    // kv half of each 64-tile
  const int b    = blockIdx.x & 7;        // XCD-affine batch
  const int n0   = (blockIdx.x >> 3) * 128;

  // ---- prologue: stage tile 0 (K + V^T) into buffer 0
  #pragma unroll
  for (int i = 0; i < 4; ++i) {
    int pbase = (i * 8 + wid) * 64;
    int p = pbase + lane;
    int row = p >> 5, sl = p & 31;
    gload_lds16(kg + ((size_t)(b * NSEQ + row)) * CDIM + (sl ^ (row & 7)) * 8,
                smem + pbase * 16);
    int d = p >> 3, vsl = p & 7;
    gload_lds16(vtg + ((size_t)(b * CDIM + d)) * NSEQ + (vsl ^ (d & 7)) * 8,
                smem + 65536 + pbase * 16);
  }

  // ---- Q fragments: B-operand of swapped MFMA. lane holds Q[q=l31][c=ks*16+hi*8+j]
  half8 qf[16];
  {
    const _Float16* qp =
        qg + ((size_t)(b * NSEQ + n0 + qg_ * 32 + l31)) * CDIM + hi * 8;
    #pragma unroll
    for (int ks = 0; ks < 16; ++ks) qf[ks] = *(const half8*)(qp + ks * 16);
  }

  f32x16 o[8];  // O[q=(r&3)+8*(r>>2)+4*hi][d=dt*32+l31], f32
  #pragma unroll
  for (int dt = 0; dt < 8; ++dt)
    #pragma unroll
    for (int r = 0; r < 16; ++r) o[dt][r] = 0.0f;
  float mrun = -1e30f, lrun = 0.0f;

  __syncthreads();  // prologue staging drained

  const int krow = kvh * 32 + l31;
  const int kxor = krow & 7;

  for (int t = 0; t < 64; ++t) {
    const int cur = t & 1;
    const char* kb = smem + cur * 32768;
    const char* vb = smem + 65536 + cur * 32768;

    // issue next tile's staging into the other buffer (drained at iter-end barrier)
    if (t < 63) {
      const int kv0n = (t + 1) * 64;
      char* kn = smem + (cur ^ 1) * 32768;
      char* vn = smem + 65536 + (cur ^ 1) * 32768;
      #pragma unroll
      for (int i = 0; i < 4; ++i) {
        int pbase = (i * 8 + wid) * 64;
        int p = pbase + lane;
        int row = p >> 5, sl = p & 31;
        gload_lds16(kg + ((size_t)(b * NSEQ + kv0n + row)) * CDIM + (sl ^ (row & 7)) * 8,
                    kn + pbase * 16);
        int d = p >> 3, vsl = p & 7;
        gload_lds16(vtg + ((size_t)(b * CDIM + d)) * NSEQ + kv0n + (vsl ^ (d & 7)) * 8,
                    vn + pbase * 16);
      }
    }

    // ---- S^T = K x Q^T : one 32x32 C-tile/wave (32 kv x 32 q), 16 k-steps
    f32x16 sacc;
    #pragma unroll
    for (int r = 0; r < 16; ++r) sacc[r] = 0.0f;
    const char* krowp = kb + krow * 512;
    #pragma unroll
    for (int ks = 0; ks < 16; ++ks) {
      half8 kf = *(const half8*)(krowp + (((ks * 2 + hi) ^ kxor) << 4));
      sacc = __builtin_amdgcn_mfma_f32_32x32x16_f16(kf, qf[ks], sacc, 0, 0, 0);
    }

    // ---- in-register online softmax (col q = l31; sacc[r] = S^T[kv=crow(r,hi)][q])
    float pm = sacc[0];
    #pragma unroll
    for (int r = 1; r < 16; ++r) pm = fmaxf(pm, sacc[r]);
    pm = fmaxf(pm, sx32f(pm));  // full 32-kv row max for this tile

    if (!__all(pm - mrun <= 8.0f)) {   // defer-max (T13), THR=8 in log2 domain
      float mnew = fmaxf(mrun, pm);
      float al = exp2f(mrun - mnew);
      mrun = mnew;
      lrun *= al;
      #pragma unroll
      for (int r = 0; r < 16; ++r) {
        float ar = __shfl(al, (r & 3) + 8 * (r >> 2) + 4 * hi, 64);
        #pragma unroll
        for (int dt = 0; dt < 8; ++dt) o[dt][r] *= ar;
      }
    }

    // exp2 IN PLACE (sacc becomes P; no separate p[16] -> -16 live regs)
    float ls = 0.0f;
    #pragma unroll
    for (int r = 0; r < 16; ++r) { sacc[r] = exp2f(sacc[r] - mrun); ls += sacc[r]; }
    lrun += ls + sx32f(ls);

    // ---- pack P -> f16 A-frags in two batches (pack temps 16 -> 8)
    half8 pa0, pa1;
    {
      uint32_t c0 = pkrtz(sacc[0], sacc[1]), c1 = pkrtz(sacc[2], sacc[3]);
      uint32_t c2 = pkrtz(sacc[4], sacc[5]), c3 = pkrtz(sacc[6], sacc[7]);
      uint32_t t0 = sx32u(c0), t1 = sx32u(c1), t2 = sx32u(c2), t3 = sx32u(c3);
      pa0 = __builtin_bit_cast(half8, (u32x4){
          hi ? t2 : c0, hi ? t3 : c1, hi ? c2 : t0, hi ? c3 : t1});
    }
    {
      uint32_t c0 = pkrtz(sacc[8], sacc[9]),  c1 = pkrtz(sacc[10], sacc[11]);
      uint32_t c2 = pkrtz(sacc[12], sacc[13]), c3 = pkrtz(sacc[14], sacc[15]);
      uint32_t t0 = sx32u(c0), t1 = sx32u(c1), t2 = sx32u(c2), t3 = sx32u(c3);
      pa1 = __builtin_bit_cast(half8, (u32x4){
          hi ? t2 : c0, hi ? t3 : c1, hi ? c2 : t0, hi ? c3 : t1});
    }

    // ---- PV: O[32q x 256d] += P[32q x 32kv] x V[32kv x 256d]
    #pragma unroll
    for (int dt = 0; dt < 8; ++dt) {
      const char* vrow = vb + (dt * 32 + l31) * 128;
      const int vx = (dt * 32 + l31) & 7;
      half8 vf0 = *(const half8*)(vrow + (((kvh * 4 + 0 + hi) ^ vx) << 4));
      half8 vf1 = *(const half8*)(vrow + (((kvh * 4 + 2 + hi) ^ vx) << 4));
      o[dt] = __builtin_amdgcn_mfma_f32_32x32x16_f16(pa0, vf0, o[dt], 0, 0, 0);
      o[dt] = __builtin_amdgcn_mfma_f32_32x32x16_f16(pa1, vf1, o[dt], 0, 0, 0);
    }

    __syncthreads();  // reads of buf[cur] done + staging into buf[cur^1] drained
  }

  // ---- epilogue: merge the two kv-half waves (wid, wid^4) via LDS
  if (lane < 32) mb[wid * 32 + lane] = mrun;
  __syncthreads();
  float mo = mb[(wid ^ 4) * 32 + l31];
  float M  = fmaxf(mrun, mo);
  float asel = exp2f(mrun - M);   // per-lane: factor for q = l31
  if (lane < 32) lb[wid * 32 + lane] = lrun * asel;
  __syncthreads();
  float lt = lrun * asel + lb[(wid ^ 4) * 32 + l31];
  float rlt = 1.0f / lt;          // per-lane: 1/l for q = l31

  float* ob = (float*)smem + (size_t)(wid & 3) * 8192;  // [32 q][256 d] f32 per pair
  if (wid >= 4) {
    #pragma unroll
    for (int r = 0; r < 16; ++r) {
      int q = (r & 3) + 8 * (r >> 2) + 4 * hi;
      float aq = __shfl(asel, q, 64);          // factor for row q, not l31
      #pragma unroll
      for (int dt = 0; dt < 8; ++dt)
        ob[q * 256 + dt * 32 + l31] = o[dt][r] * aq;
    }
  }
  __syncthreads();
  if (wid < 4) {
    #pragma unroll
    for (int r = 0; r < 16; ++r) {
      int q = (r & 3) + 8 * (r >> 2) + 4 * hi;
      float aq = __shfl(asel, q, 64);          // factor for row q
      float rq = __shfl(rlt, q, 64);
      #pragma unroll
      for (int dt = 0; dt < 8; ++dt) {
        float v = o[dt][r] * aq + ob[q * 256 + dt * 32 + l31];
        og[((size_t)(b * NSEQ + n0 + qg_ * 32 + q)) * CDIM + dt * 32 + l31] =
            (_Float16)(v * rq);
      }
    }
  }
}

// ---------------- launcher
extern "C" void kernel_launch(void* const* d_in, const int* in_sizes, int n_in,
                              void* d_out, int out_size, void* d_ws, size_t ws_size,
                              hipStream_t stream) {
  const float* x   = (const float*)d_in[0];
  const float* gam = (const float*)d_in[1];
  const float* bet = (const float*)d_in[2];
  const float* wq  = (const float*)d_in[3];
  const float* bq  = (const float*)d_in[4];
  const float* wk  = (const float*)d_in[5];
  const float* bk  = (const float*)d_in[6];
  const float* wv  = (const float*)d_in[7];
  const float* bv  = (const float*)d_in[8];
  const float* wp  = (const float*)d_in[9];
  const float* bp  = (const float*)d_in[10];
  float* out = (float*)d_out;

  char* ws = (char*)d_ws;
  float*    xnf = (float*)ws;                             // 32MB fp32 xn (residual)
  _Float16* xnh = (_Float16*)(ws + (32u << 20));          // 16MB f16 xn
  _Float16* qh  = (_Float16*)(ws + (48u << 20));          // 16MB q (scaled)
  _Float16* kh  = (_Float16*)(ws + (64u << 20));          // 16MB k
  _Float16* vth = (_Float16*)(ws + (80u << 20));          // 16MB v^T [b][c][n]
  _Float16* oh  = (_Float16*)(ws + (96u << 20));          // 16MB attn out

  (void)hipFuncSetAttribute((const void*)proj_kernel,
                            hipFuncAttributeMaxDynamicSharedMemorySize, 65536);
  (void)hipFuncSetAttribute((const void*)attn_kernel,
                            hipFuncAttributeMaxDynamicSharedMemorySize, ATTN_LDS);

  ln_kernel<<<NTOK / 4, 256, 0, stream>>>(x, gam, bet, xnf, xnh);
  proj_kernel<<<dim3(64, 4, 3), 256, 65536, stream>>>(
      xnh, wq, bq, wk, bk, wv, bv, wp, bp, qh, kh, vth, xnf, out, 0);
  attn_kernel<<<256, 512, ATTN_LDS, stream>>>(qh, kh, vth, oh);
  proj_kernel<<<dim3(64, 4, 1), 256, 65536, stream>>>(
      oh, wq, bq, wk, bk, wv, bv, wp, bp, qh, kh, vth, xnf, out, 3);
}

// Round 12
// 273.761 us; speedup vs baseline: 1.1720x; 1.0106x over previous
//
#include <hip/hip_runtime.h>
#include <cstdint>

#define NB    8
#define NSEQ  4096
#define CDIM  256
#define NTOK  (NB*NSEQ)

typedef _Float16 half8  __attribute__((ext_vector_type(8)));
typedef _Float16 half4v __attribute__((ext_vector_type(4)));
typedef float    f32x4  __attribute__((ext_vector_type(4)));
typedef float    f32x16 __attribute__((ext_vector_type(16)));
typedef uint32_t u32x4  __attribute__((ext_vector_type(4)));

typedef unsigned int u32_g __attribute__((address_space(1)));
typedef unsigned int u32_l __attribute__((address_space(3)));

// direct global->LDS, 16B per lane; LDS dest = wave-uniform base + lane*16
__device__ __forceinline__ void gload_lds16(const void* g, void* l) {
  __builtin_amdgcn_global_load_lds((u32_g*)(uintptr_t)g,
                                   (u32_l*)(uint32_t)(uintptr_t)l, 16, 0, 0);
}

__device__ __forceinline__ uint32_t pkrtz(float a, float b) {
  auto h = __builtin_amdgcn_cvt_pkrtz(a, b);  // lo16 = a, hi16 = b
  return __builtin_bit_cast(uint32_t, h);
}
// lane^32 exchange via shfl (semantics-certain)
__device__ __forceinline__ float sx32f(float v) { return __shfl_xor(v, 32, 64); }
__device__ __forceinline__ uint32_t sx32u(uint32_t v) {
  return (uint32_t)__shfl_xor((int)v, 32, 64);
}

// ---------------- LayerNorm: one wave per token; f16 xn only (residual reads xnh)
__global__ __launch_bounds__(256) void ln_kernel(
    const float* __restrict__ x, const float* __restrict__ gam,
    const float* __restrict__ bet, _Float16* __restrict__ xnh) {
  const int lane = threadIdx.x & 63;
  const size_t tok = (size_t)blockIdx.x * 4 + (threadIdx.x >> 6);
  const float4 v = ((const float4*)(x + tok * CDIM))[lane];
  float s  = v.x + v.y + v.z + v.w;
  float s2 = v.x*v.x + v.y*v.y + v.z*v.z + v.w*v.w;
  #pragma unroll
  for (int m = 1; m < 64; m <<= 1) {
    s  += __shfl_xor(s,  m, 64);
    s2 += __shfl_xor(s2, m, 64);
  }
  const float mean = s * (1.0f / CDIM);
  const float rstd = rsqrtf(s2 * (1.0f / CDIM) - mean * mean + 1e-3f);
  const float4 gv = ((const float4*)gam)[lane];
  const float4 bv = ((const float4*)bet)[lane];
  half4v h;
  h[0] = (_Float16)((v.x - mean) * rstd * gv.x + bv.x);
  h[1] = (_Float16)((v.y - mean) * rstd * gv.y + bv.y);
  h[2] = (_Float16)((v.z - mean) * rstd * gv.z + bv.z);
  h[3] = (_Float16)((v.w - mean) * rstd * gv.w + bv.w);
  ((half4v*)(xnh + tok * CDIM))[lane] = h;
}

// ---------------- projection GEMM (R1 structure; mode-3 residual now from f16 xnh)
__global__ __launch_bounds__(256, 2) void proj_kernel(
    const _Float16* __restrict__ inh,
    const float* __restrict__ wq_, const float* __restrict__ bq_,
    const float* __restrict__ wk_, const float* __restrict__ bk_,
    const float* __restrict__ wv_, const float* __restrict__ bv_,
    const float* __restrict__ wp_, const float* __restrict__ bp_,
    _Float16* __restrict__ qg, _Float16* __restrict__ kg, _Float16* __restrict__ vtg,
    const _Float16* __restrict__ residh, float* __restrict__ outf,
    int mode_base) {
  extern __shared__ char smem[];
  const int mode = mode_base + blockIdx.z;
  const float* wsel = (mode == 0) ? wq_ : (mode == 1) ? wk_ : (mode == 2) ? wv_ : wp_;
  const float* bsel = (mode == 0) ? bq_ : (mode == 1) ? bk_ : (mode == 2) ? bv_ : bp_;

  const int tid = threadIdx.x;
  const int lane = tid & 63;
  const int wid  = tid >> 6;     // 0..3
  const int g    = lane >> 4;    // 0..3
  const int lr   = lane & 15;
  const int jstrip = blockIdx.y; // 0..3
  const size_t tok0 = (size_t)blockIdx.x * 512;

  char* wt   = smem;             // [64 j][256 c] f16, XOR-swizzled (32KB)
  char* tile = smem + 32768;     // [64 tok][256 c] f16, swizzled (32KB)

  for (int i = 0; i < 64; ++i) {
    int idx = i * 256 + tid;
    int c = idx >> 6, j = idx & 63;
    float val = wsel[(size_t)c * CDIM + jstrip * 64 + j];
    *(_Float16*)(wt + j * 512 + ((((c >> 3) ^ (j & 7))) << 4) + ((c & 7) << 1)) =
        (_Float16)val;
  }
  float bjv[4];
  #pragma unroll
  for (int jc = 0; jc < 4; ++jc) bjv[jc] = bsel[jstrip * 64 + jc * 16 + lr];
  __syncthreads();

  for (int t = 0; t < 8; ++t) {
    const size_t trow0 = tok0 + t * 64;
    #pragma unroll
    for (int i = 0; i < 8; ++i) {
      int pbase = (i * 4 + wid) * 64;
      int p = pbase + lane;
      int row = p >> 5, sl = p & 31;
      gload_lds16(inh + (trow0 + row) * CDIM + (size_t)((sl ^ (row & 7)) * 8),
                  tile + pbase * 16);
    }
    __syncthreads();

    f32x4 acc[4] = {{0,0,0,0},{0,0,0,0},{0,0,0,0},{0,0,0,0}};
    #pragma unroll
    for (int kc = 0; kc < 8; ++kc) {
      half8 a = *(const half8*)(tile + (wid * 16 + lr) * 512 +
                                ((((kc << 2) | g) ^ (lr & 7)) << 4));
      #pragma unroll
      for (int jc = 0; jc < 4; ++jc) {
        half8 bf = *(const half8*)(wt + (jc * 16 + lr) * 512 +
                                   ((((kc << 2) | g) ^ (lr & 7)) << 4));
        acc[jc] = __builtin_amdgcn_mfma_f32_16x16x32_f16(a, bf, acc[jc], 0, 0, 0);
      }
    }

    if (mode == 3) {
      #pragma unroll
      for (int jc = 0; jc < 4; ++jc) {
        #pragma unroll
        for (int r = 0; r < 4; ++r) {
          size_t row = trow0 + wid * 16 + g * 4 + r;
          size_t off = row * CDIM + jstrip * 64 + jc * 16 + lr;
          outf[off] = acc[jc][r] + bjv[jc] + (float)residh[off];
        }
      }
    } else {
      const float csc = (mode == 0) ? 0.09016844005556021f : 1.0f; // log2(e)/16
      __syncthreads();
      _Float16* ot = (_Float16*)tile;  // [64][72]
      #pragma unroll
      for (int jc = 0; jc < 4; ++jc)
        #pragma unroll
        for (int r = 0; r < 4; ++r)
          ot[(wid * 16 + g * 4 + r) * 72 + jc * 16 + lr] =
              (_Float16)((acc[jc][r] + bjv[jc]) * csc);
      __syncthreads();
      if (mode != 2) {
        _Float16* dst = (mode == 0) ? qg : kg;
        #pragma unroll
        for (int it = 0; it < 2; ++it) {
          int s = it * 256 + tid;
          int row = s >> 3, sl = s & 7;
          half8 vv = *(const half8*)(ot + row * 72 + sl * 8);
          *(half8*)(dst + (trow0 + row) * CDIM + jstrip * 64 + sl * 8) = vv;
        }
      } else {
        #pragma unroll
        for (int it = 0; it < 2; ++it) {
          int s = it * 256 + tid;
          int j = s >> 3, ns = s & 7;
          half8 vv;
          #pragma unroll
          for (int e = 0; e < 8; ++e) vv[e] = ot[(ns * 8 + e) * 72 + j];
          size_t bb  = trow0 >> 12;
          size_t nin = (trow0 & 4095) + ns * 8;
          *(half8*)(vtg + ((size_t)bb * CDIM + jstrip * 64 + j) * NSEQ + nin) = vv;
        }
      }
    }
    __syncthreads();
  }
}

// ---------------- flash attention v10: split-KV, 4-wave blocks, 2 blocks/CU
// Each block: 128 q x 2048 kv (one kv-half). 4 waves = 4 q-groups; each wave
// owns the FULL 32-kv tile (no kvh split -> no intra-block merge). Per-wave
// math identical to R11 (16 S-MFMA + 16 PV-MFMA / iter, swapped QK^T,
// in-register softmax, in-place exp2, batched pack). Grid 512 = 2 blocks/CU
// (LDS 64KB/block): independent barriers desynchronize the two blocks'
// S/softmax/PV phases -> LDS port + SIMD stay fed (R11 wall was lockstep
// phase-bunching at 2 waves/SIMD, LDS port only ~55% busy).
// Epilogue: store UNNORMALIZED O (f16) + per-row m,l; merge_kernel combines.
// LDS: K dbuf 2x16KB @0, V dbuf 2x16KB @32768 = 65536 B.
#define ATTN_LDS 65536

__global__ __launch_bounds__(256)
__attribute__((amdgpu_waves_per_eu(2, 2)))
void attn_kernel(
    const _Float16* __restrict__ qg, const _Float16* __restrict__ kg,
    const _Float16* __restrict__ vtg, _Float16* __restrict__ po,
    float* __restrict__ mbuf, float* __restrict__ lbuf) {
  extern __shared__ char smem[];

  const int tid  = threadIdx.x;
  const int lane = tid & 63;
  const int wid  = tid >> 6;    // 0..3 = q-group
  const int l31  = lane & 31;
  const int hi   = lane >> 5;   // 0/1
  const int bid  = blockIdx.x;
  const int b    = bid & 7;               // XCD-affine batch
  const int kvh  = (bid >> 3) & 1;        // kv half
  const int n0   = (bid >> 4) * 128;      // q-tile base
  const int kvbase = kvh * 2048;

  // ---- prologue: stage tile 0 (K [32][512B] + V^T [256][64B]) into buffer 0
  #pragma unroll
  for (int i = 0; i < 4; ++i) {
    int pbase = (i * 4 + wid) * 64;
    int p = pbase + lane;                 // 0..1023 slots of 16B
    int row = p >> 5, sl = p & 31;        // K: 32 rows x 32 slots
    gload_lds16(kg + ((size_t)(b * NSEQ + kvbase + row)) * CDIM + (sl ^ (row & 7)) * 8,
                smem + pbase * 16);
    int d = p >> 2, vsl = p & 3;          // V^T: 256 d x 4 slots
    gload_lds16(vtg + ((size_t)(b * CDIM + d)) * NSEQ + kvbase + (vsl ^ (d & 3)) * 8,
                smem + 32768 + pbase * 16);
  }

  // ---- Q fragments: B-operand of swapped MFMA. lane holds Q[q=l31][c=ks*16+hi*8+j]
  half8 qf[16];
  {
    const _Float16* qp =
        qg + ((size_t)(b * NSEQ + n0 + wid * 32 + l31)) * CDIM + hi * 8;
    #pragma unroll
    for (int ks = 0; ks < 16; ++ks) qf[ks] = *(const half8*)(qp + ks * 16);
  }

  f32x16 o[8];  // O[q=(r&3)+8*(r>>2)+4*hi][d=dt*32+l31], f32 (unnormalized)
  #pragma unroll
  for (int dt = 0; dt < 8; ++dt)
    #pragma unroll
    for (int r = 0; r < 16; ++r) o[dt][r] = 0.0f;
  float mrun = -1e30f, lrun = 0.0f;

  __syncthreads();  // prologue staging drained

  const int kxor = l31 & 7;

  for (int t = 0; t < 64; ++t) {
    const int cur = t & 1;
    const char* kb = smem + cur * 16384;
    const char* vb = smem + 32768 + cur * 16384;

    // issue next tile's staging into the other buffer (drained at iter-end barrier)
    if (t < 63) {
      const int kv0n = kvbase + (t + 1) * 32;
      char* kn = smem + (cur ^ 1) * 16384;
      char* vn = smem + 32768 + (cur ^ 1) * 16384;
      #pragma unroll
      for (int i = 0; i < 4; ++i) {
        int pbase = (i * 4 + wid) * 64;
        int p = pbase + lane;
        int row = p >> 5, sl = p & 31;
        gload_lds16(kg + ((size_t)(b * NSEQ + kv0n + row)) * CDIM + (sl ^ (row & 7)) * 8,
                    kn + pbase * 16);
        int d = p >> 2, vsl = p & 3;
        gload_lds16(vtg + ((size_t)(b * CDIM + d)) * NSEQ + kv0n + (vsl ^ (d & 3)) * 8,
                    vn + pbase * 16);
      }
    }

    // ---- S^T = K x Q^T : one 32x32 C-tile/wave (32 kv x 32 q), 16 k-steps
    f32x16 sacc;
    #pragma unroll
    for (int r = 0; r < 16; ++r) sacc[r] = 0.0f;
    const char* krowp = kb + l31 * 512;
    #pragma unroll
    for (int ks = 0; ks < 16; ++ks) {
      half8 kf = *(const half8*)(krowp + (((ks * 2 + hi) ^ kxor) << 4));
      sacc = __builtin_amdgcn_mfma_f32_32x32x16_f16(kf, qf[ks], sacc, 0, 0, 0);
    }

    // ---- in-register online softmax (col q = l31; sacc[r] = S^T[kv=crow(r,hi)][q])
    float pm = sacc[0];
    #pragma unroll
    for (int r = 1; r < 16; ++r) pm = fmaxf(pm, sacc[r]);
    pm = fmaxf(pm, sx32f(pm));  // full 32-kv row max for this tile

    if (!__all(pm - mrun <= 8.0f)) {   // defer-max (T13), THR=8 in log2 domain
      float mnew = fmaxf(mrun, pm);
      float al = exp2f(mrun - mnew);
      mrun = mnew;
      lrun *= al;
      #pragma unroll
      for (int r = 0; r < 16; ++r) {
        float ar = __shfl(al, (r & 3) + 8 * (r >> 2) + 4 * hi, 64);
        #pragma unroll
        for (int dt = 0; dt < 8; ++dt) o[dt][r] *= ar;
      }
    }

    // exp2 in place (sacc becomes P)
    float ls = 0.0f;
    #pragma unroll
    for (int r = 0; r < 16; ++r) { sacc[r] = exp2f(sacc[r] - mrun); ls += sacc[r]; }
    lrun += ls + sx32f(ls);

    // ---- pack P -> f16 A-frags in two batches
    half8 pa0, pa1;
    {
      uint32_t c0 = pkrtz(sacc[0], sacc[1]), c1 = pkrtz(sacc[2], sacc[3]);
      uint32_t c2 = pkrtz(sacc[4], sacc[5]), c3 = pkrtz(sacc[6], sacc[7]);
      uint32_t t0 = sx32u(c0), t1 = sx32u(c1), t2 = sx32u(c2), t3 = sx32u(c3);
      pa0 = __builtin_bit_cast(half8, (u32x4){
          hi ? t2 : c0, hi ? t3 : c1, hi ? c2 : t0, hi ? c3 : t1});
    }
    {
      uint32_t c0 = pkrtz(sacc[8], sacc[9]),  c1 = pkrtz(sacc[10], sacc[11]);
      uint32_t c2 = pkrtz(sacc[12], sacc[13]), c3 = pkrtz(sacc[14], sacc[15]);
      uint32_t t0 = sx32u(c0), t1 = sx32u(c1), t2 = sx32u(c2), t3 = sx32u(c3);
      pa1 = __builtin_bit_cast(half8, (u32x4){
          hi ? t2 : c0, hi ? t3 : c1, hi ? c2 : t0, hi ? c3 : t1});
    }

    // ---- PV: O[32q x 256d] += P[32q x 32kv] x V[32kv x 256d]
    #pragma unroll
    for (int dt = 0; dt < 8; ++dt) {
      const char* vrow = vb + (dt * 32 + l31) * 64;
      const int vx = (dt * 32 + l31) & 3;
      half8 vf0 = *(const half8*)(vrow + (((0 + hi) ^ vx) << 4));
      half8 vf1 = *(const half8*)(vrow + (((2 + hi) ^ vx) << 4));
      o[dt] = __builtin_amdgcn_mfma_f32_32x32x16_f16(pa0, vf0, o[dt], 0, 0, 0);
      o[dt] = __builtin_amdgcn_mfma_f32_32x32x16_f16(pa1, vf1, o[dt], 0, 0, 0);
    }

    __syncthreads();  // reads of buf[cur] done + staging into buf[cur^1] drained
  }

  // ---- epilogue: store unnormalized partials (no intra-block merge needed)
  const size_t tok0 = (size_t)b * NSEQ + n0 + wid * 32;
  if (lane < 32) {
    mbuf[(size_t)kvh * NTOK + tok0 + l31] = mrun;
    lbuf[(size_t)kvh * NTOK + tok0 + l31] = lrun;
  }
  #pragma unroll
  for (int r = 0; r < 16; ++r) {
    int q = (r & 3) + 8 * (r >> 2) + 4 * hi;
    _Float16* prow = po + ((size_t)kvh * NTOK + tok0 + q) * CDIM + l31;
    #pragma unroll
    for (int dt = 0; dt < 8; ++dt)
      prow[dt * 32] = (_Float16)o[dt][r];
  }
}

// ---------------- merge: combine the two kv-half partials per token
__global__ __launch_bounds__(256) void merge_kernel(
    const _Float16* __restrict__ po, const float* __restrict__ mbuf,
    const float* __restrict__ lbuf, _Float16* __restrict__ og) {
  const int lane = threadIdx.x & 63;
  const size_t tok = (size_t)blockIdx.x * 4 + (threadIdx.x >> 6);
  const float m0 = mbuf[tok], m1 = mbuf[NTOK + tok];
  const float l0 = lbuf[tok], l1 = lbuf[NTOK + tok];
  const float mm = fmaxf(m0, m1);
  const float a0 = exp2f(m0 - mm), a1 = exp2f(m1 - mm);
  const float rl = 1.0f / (l0 * a0 + l1 * a1);
  const half4v o0 = ((const half4v*)(po + tok * CDIM))[lane];
  const half4v o1 = ((const half4v*)(po + ((size_t)NTOK + tok) * CDIM))[lane];
  half4v out;
  #pragma unroll
  for (int j = 0; j < 4; ++j)
    out[j] = (_Float16)(((float)o0[j] * a0 + (float)o1[j] * a1) * rl);
  ((half4v*)(og + tok * CDIM))[lane] = out;
}

// ---------------- launcher
extern "C" void kernel_launch(void* const* d_in, const int* in_sizes, int n_in,
                              void* d_out, int out_size, void* d_ws, size_t ws_size,
                              hipStream_t stream) {
  const float* x   = (const float*)d_in[0];
  const float* gam = (const float*)d_in[1];
  const float* bet = (const float*)d_in[2];
  const float* wq  = (const float*)d_in[3];
  const float* bq  = (const float*)d_in[4];
  const float* wk  = (const float*)d_in[5];
  const float* bk  = (const float*)d_in[6];
  const float* wv  = (const float*)d_in[7];
  const float* bv  = (const float*)d_in[8];
  const float* wp  = (const float*)d_in[9];
  const float* bp  = (const float*)d_in[10];
  float* out = (float*)d_out;

  char* ws = (char*)d_ws;
  _Float16* po  = (_Float16*)ws;                          // 32MB: partial O x2 halves
  _Float16* xnh = (_Float16*)(ws + (32u << 20));          // 16MB f16 xn
  _Float16* qh  = (_Float16*)(ws + (48u << 20));          // 16MB q (scaled)
  _Float16* kh  = (_Float16*)(ws + (64u << 20));          // 16MB k
  _Float16* vth = (_Float16*)(ws + (80u << 20));          // 16MB v^T [b][c][n]
  _Float16* oh  = (_Float16*)(ws + (96u << 20));          // 16MB attn out (merged)
  float*    mbf = (float*)(ws + (112u << 20));            // 256KB m x2 halves
  float*    lbf = (float*)(ws + (112u << 20) + (1u << 18)); // 256KB l x2 halves

  (void)hipFuncSetAttribute((const void*)proj_kernel,
                            hipFuncAttributeMaxDynamicSharedMemorySize, 65536);
  (void)hipFuncSetAttribute((const void*)attn_kernel,
                            hipFuncAttributeMaxDynamicSharedMemorySize, ATTN_LDS);

  ln_kernel<<<NTOK / 4, 256, 0, stream>>>(x, gam, bet, xnh);
  proj_kernel<<<dim3(64, 4, 3), 256, 65536, stream>>>(
      xnh, wq, bq, wk, bk, wv, bv, wp, bp, qh, kh, vth, xnh, out, 0);
  attn_kernel<<<512, 256, ATTN_LDS, stream>>>(qh, kh, vth, po, mbf, lbf);
  merge_kernel<<<NTOK / 4, 256, 0, stream>>>(po, mbf, lbf, oh);
  proj_kernel<<<dim3(64, 4, 1), 256, 65536, stream>>>(
      oh, wq, bq, wk, bk, wv, bv, wp, bp, qh, kh, vth, xnh, out, 3);
}

// Round 13
// 228.391 us; speedup vs baseline: 1.4048x; 1.1986x over previous
//
#include <hip/hip_runtime.h>
#include <cstdint>

#define NB    8
#define NSEQ  4096
#define CDIM  256
#define NTOK  (NB*NSEQ)

typedef _Float16 half8  __attribute__((ext_vector_type(8)));
typedef _Float16 half4v __attribute__((ext_vector_type(4)));
typedef float    f32x4  __attribute__((ext_vector_type(4)));
typedef float    f32x16 __attribute__((ext_vector_type(16)));
typedef uint32_t u32x4  __attribute__((ext_vector_type(4)));
typedef unsigned long u64x2 __attribute__((ext_vector_type(2)));

typedef unsigned int u32_g __attribute__((address_space(1)));
typedef unsigned int u32_l __attribute__((address_space(3)));

// direct global->LDS, 16B per lane; LDS dest = wave-uniform base + lane*16
__device__ __forceinline__ void gload_lds16(const void* g, void* l) {
  __builtin_amdgcn_global_load_lds((u32_g*)(uintptr_t)g,
                                   (u32_l*)(uint32_t)(uintptr_t)l, 16, 0, 0);
}

__device__ __forceinline__ uint32_t pkrtz(float a, float b) {
  auto h = __builtin_amdgcn_cvt_pkrtz(a, b);  // lo16 = a, hi16 = b
  return __builtin_bit_cast(uint32_t, h);
}
__device__ __forceinline__ uint8_t to_fp8(float v) {
  return (uint8_t)(__builtin_amdgcn_cvt_pk_fp8_f32(v, v, 0, false) & 0xff);
}
// lane^32 exchange via shfl (semantics-certain)
__device__ __forceinline__ float sx32f(float v) { return __shfl_xor(v, 32, 64); }
__device__ __forceinline__ uint32_t sx32u(uint32_t v) {
  return (uint32_t)__shfl_xor((int)v, 32, 64);
}

// ---------------- LayerNorm: one wave per token; f16 xn only
__global__ __launch_bounds__(256) void ln_kernel(
    const float* __restrict__ x, const float* __restrict__ gam,
    const float* __restrict__ bet, _Float16* __restrict__ xnh) {
  const int lane = threadIdx.x & 63;
  const size_t tok = (size_t)blockIdx.x * 4 + (threadIdx.x >> 6);
  const float4 v = ((const float4*)(x + tok * CDIM))[lane];
  float s  = v.x + v.y + v.z + v.w;
  float s2 = v.x*v.x + v.y*v.y + v.z*v.z + v.w*v.w;
  #pragma unroll
  for (int m = 1; m < 64; m <<= 1) {
    s  += __shfl_xor(s,  m, 64);
    s2 += __shfl_xor(s2, m, 64);
  }
  const float mean = s * (1.0f / CDIM);
  const float rstd = rsqrtf(s2 * (1.0f / CDIM) - mean * mean + 1e-3f);
  const float4 gv = ((const float4*)gam)[lane];
  const float4 bv = ((const float4*)bet)[lane];
  half4v h;
  h[0] = (_Float16)((v.x - mean) * rstd * gv.x + bv.x);
  h[1] = (_Float16)((v.y - mean) * rstd * gv.y + bv.y);
  h[2] = (_Float16)((v.z - mean) * rstd * gv.z + bv.z);
  h[3] = (_Float16)((v.w - mean) * rstd * gv.w + bv.w);
  ((half4v*)(xnh + tok * CDIM))[lane] = h;
}

// ---------------- projection GEMM
// modes: 0=Q (fp8 out, scale log2e folded), 1=K (fp8 out), 2=V (f16 [b][c][n]),
//        3=P (fp32 + residual).
// fp8 rows use a hi-split layout: byte(m,hi,j) = (m>>1)*32 + hi*16 + (m&1)*8 + j
// where c = m*16 + hi*8 + j  ->  one 16B LDS read in attn = TWO 8B A-frags.
__global__ __launch_bounds__(256, 2) void proj_kernel(
    const _Float16* __restrict__ inh,
    const float* __restrict__ wq_, const float* __restrict__ bq_,
    const float* __restrict__ wk_, const float* __restrict__ bk_,
    const float* __restrict__ wv_, const float* __restrict__ bv_,
    const float* __restrict__ wp_, const float* __restrict__ bp_,
    uint8_t* __restrict__ qg8, uint8_t* __restrict__ kg8,
    _Float16* __restrict__ vtg,
    const _Float16* __restrict__ residh, float* __restrict__ outf,
    int mode_base) {
  extern __shared__ char smem[];
  const int mode = mode_base + blockIdx.z;
  const float* wsel = (mode == 0) ? wq_ : (mode == 1) ? wk_ : (mode == 2) ? wv_ : wp_;
  const float* bsel = (mode == 0) ? bq_ : (mode == 1) ? bk_ : (mode == 2) ? bv_ : bp_;

  const int tid = threadIdx.x;
  const int lane = tid & 63;
  const int wid  = tid >> 6;     // 0..3
  const int g    = lane >> 4;    // 0..3
  const int lr   = lane & 15;
  const int jstrip = blockIdx.y; // 0..3
  const size_t tok0 = (size_t)blockIdx.x * 512;

  char* wt   = smem;             // [64 j][256 c] f16, XOR-swizzled (32KB)
  char* tile = smem + 32768;     // [64 tok][256 c] f16, swizzled (32KB)

  for (int i = 0; i < 64; ++i) {
    int idx = i * 256 + tid;
    int c = idx >> 6, j = idx & 63;
    float val = wsel[(size_t)c * CDIM + jstrip * 64 + j];
    *(_Float16*)(wt + j * 512 + ((((c >> 3) ^ (j & 7))) << 4) + ((c & 7) << 1)) =
        (_Float16)val;
  }
  float bjv[4];
  #pragma unroll
  for (int jc = 0; jc < 4; ++jc) bjv[jc] = bsel[jstrip * 64 + jc * 16 + lr];
  __syncthreads();

  for (int t = 0; t < 8; ++t) {
    const size_t trow0 = tok0 + t * 64;
    #pragma unroll
    for (int i = 0; i < 8; ++i) {
      int pbase = (i * 4 + wid) * 64;
      int p = pbase + lane;
      int row = p >> 5, sl = p & 31;
      gload_lds16(inh + (trow0 + row) * CDIM + (size_t)((sl ^ (row & 7)) * 8),
                  tile + pbase * 16);
    }
    __syncthreads();

    f32x4 acc[4] = {{0,0,0,0},{0,0,0,0},{0,0,0,0},{0,0,0,0}};
    #pragma unroll
    for (int kc = 0; kc < 8; ++kc) {
      half8 a = *(const half8*)(tile + (wid * 16 + lr) * 512 +
                                ((((kc << 2) | g) ^ (lr & 7)) << 4));
      #pragma unroll
      for (int jc = 0; jc < 4; ++jc) {
        half8 bf = *(const half8*)(wt + (jc * 16 + lr) * 512 +
                                   ((((kc << 2) | g) ^ (lr & 7)) << 4));
        acc[jc] = __builtin_amdgcn_mfma_f32_16x16x32_f16(a, bf, acc[jc], 0, 0, 0);
      }
    }

    if (mode == 3) {
      #pragma unroll
      for (int jc = 0; jc < 4; ++jc) {
        #pragma unroll
        for (int r = 0; r < 4; ++r) {
          size_t row = trow0 + wid * 16 + g * 4 + r;
          size_t off = row * CDIM + jstrip * 64 + jc * 16 + lr;
          outf[off] = acc[jc][r] + bjv[jc] + (float)residh[off];
        }
      }
    } else if (mode <= 1) {
      // fp8 path (Q: scale log2(e); K: 1.0), hi-split byte layout
      const float csc = (mode == 0) ? 1.44269504f : 1.0f;
      __syncthreads();
      uint8_t* ot8 = (uint8_t*)tile;  // [64 tok][64 B] (this jstrip's segment)
      #pragma unroll
      for (int jc = 0; jc < 4; ++jc) {
        #pragma unroll
        for (int r = 0; r < 4; ++r) {
          int row = wid * 16 + g * 4 + r;
          int pos = (jc >> 1) * 32 + (lr >> 3) * 16 + (jc & 1) * 8 + (lr & 7);
          ot8[row * 64 + pos] = to_fp8((acc[jc][r] + bjv[jc]) * csc);
        }
      }
      __syncthreads();
      uint8_t* dst8 = (mode == 0) ? qg8 : kg8;
      int row = tid >> 2, s = tid & 3;   // 64 rows x 4 x 16B
      *(u32x4*)(dst8 + (trow0 + row) * 256 + jstrip * 64 + s * 16) =
          *(const u32x4*)(ot8 + row * 64 + s * 16);
    } else {
      __syncthreads();
      _Float16* ot = (_Float16*)tile;  // [64][72]
      #pragma unroll
      for (int jc = 0; jc < 4; ++jc)
        #pragma unroll
        for (int r = 0; r < 4; ++r)
          ot[(wid * 16 + g * 4 + r) * 72 + jc * 16 + lr] =
              (_Float16)(acc[jc][r] + bjv[jc]);
      __syncthreads();
      #pragma unroll
      for (int it = 0; it < 2; ++it) {   // transposed store vt[b][c][n]
        int s = it * 256 + tid;
        int j = s >> 3, ns = s & 7;
        half8 vv;
        #pragma unroll
        for (int e = 0; e < 8; ++e) vv[e] = ot[(ns * 8 + e) * 72 + j];
        size_t bb  = trow0 >> 12;
        size_t nin = (trow0 & 4095) + ns * 8;
        *(half8*)(vtg + ((size_t)bb * CDIM + jstrip * 64 + j) * NSEQ + nin) = vv;
      }
    }
    __syncthreads();
  }
}

// ---------------- flash attention v11: split-KV (R12 frame) + fp8 Q*K S-phase
// S-phase: mfma_f32_32x32x16_fp8_fp8, one b128 read = TWO A-frags -> 8 reads
// (was 16). qf 64->32 regs. V/P stay f16 (PV unchanged from R12).
// LDS: K dbuf 2x8KB @0, V dbuf 2x16KB @16384 = 49152 B; 2 blocks/CU.
#define ATTN_LDS 49152

__global__ __launch_bounds__(256)
__attribute__((amdgpu_waves_per_eu(2, 2)))
void attn_kernel(
    const uint8_t* __restrict__ qg8, const uint8_t* __restrict__ kg8,
    const _Float16* __restrict__ vtg, _Float16* __restrict__ po,
    float* __restrict__ mbuf, float* __restrict__ lbuf) {
  extern __shared__ char smem[];

  const int tid  = threadIdx.x;
  const int lane = tid & 63;
  const int wid  = tid >> 6;    // 0..3 = q-group
  const int l31  = lane & 31;
  const int hi   = lane >> 5;   // 0/1
  const int bid  = blockIdx.x;
  const int b    = bid & 7;               // XCD-affine batch
  const int kvh  = (bid >> 3) & 1;        // kv half
  const int n0   = (bid >> 4) * 128;      // q-tile base
  const int kvbase = kvh * 2048;

  // ---- prologue: stage tile 0 (K fp8 [32][256B] + V^T f16 [256][64B]) into buf 0
  #pragma unroll
  for (int i = 0; i < 2; ++i) {   // K: 512 slots of 16B
    int slot = i * 256 + wid * 64 + lane;
    int row = slot >> 4, s = slot & 15;
    gload_lds16(kg8 + ((size_t)(b * NSEQ + kvbase + row)) * 256 + ((s ^ (row & 7)) << 4),
                smem + slot * 16);
  }
  #pragma unroll
  for (int i = 0; i < 4; ++i) {   // V: 1024 slots of 16B
    int p = (i * 4 + wid) * 64 + lane;
    int d = p >> 2, vsl = p & 3;
    gload_lds16(vtg + ((size_t)(b * CDIM + d)) * NSEQ + kvbase + (vsl ^ (d & 3)) * 8,
                smem + 16384 + p * 16);
  }

  // ---- Q fragments (fp8): lane holds Q[q=l31][c = m*16 + hi*8 + j], 8 B per frag
  long qf8[16];
  {
    const uint8_t* qp8 = qg8 + ((size_t)(b * NSEQ + n0 + wid * 32 + l31)) * 256;
    #pragma unroll
    for (int p = 0; p < 8; ++p) {
      u64x2 qq = *(const u64x2*)(qp8 + (2 * p + hi) * 16);
      qf8[2 * p]     = (long)qq.x;
      qf8[2 * p + 1] = (long)qq.y;
    }
  }

  f32x16 o[8];  // O[q=(r&3)+8*(r>>2)+4*hi][d=dt*32+l31], f32 (unnormalized)
  #pragma unroll
  for (int dt = 0; dt < 8; ++dt)
    #pragma unroll
    for (int r = 0; r < 16; ++r) o[dt][r] = 0.0f;
  float mrun = -1e30f, lrun = 0.0f;

  __syncthreads();  // prologue staging drained

  for (int t = 0; t < 64; ++t) {
    const int cur = t & 1;
    const char* kb = smem + cur * 8192;
    const char* vb = smem + 16384 + cur * 16384;

    // issue next tile's staging into the other buffer
    if (t < 63) {
      const int kv0n = kvbase + (t + 1) * 32;
      char* kn = smem + (cur ^ 1) * 8192;
      char* vn = smem + 16384 + (cur ^ 1) * 16384;
      #pragma unroll
      for (int i = 0; i < 2; ++i) {
        int slot = i * 256 + wid * 64 + lane;
        int row = slot >> 4, s = slot & 15;
        gload_lds16(kg8 + ((size_t)(b * NSEQ + kv0n + row)) * 256 + ((s ^ (row & 7)) << 4),
                    kn + slot * 16);
      }
      #pragma unroll
      for (int i = 0; i < 4; ++i) {
        int p = (i * 4 + wid) * 64 + lane;
        int d = p >> 2, vsl = p & 3;
        gload_lds16(vtg + ((size_t)(b * CDIM + d)) * NSEQ + kv0n + (vsl ^ (d & 3)) * 8,
                    vn + p * 16);
      }
    }

    // ---- S^T = K x Q^T (fp8): 16 MFMA, 8 LDS reads (b128 = 2 A-frags)
    f32x16 sacc;
    #pragma unroll
    for (int r = 0; r < 16; ++r) sacc[r] = 0.0f;
    const char* krowp = kb + l31 * 256;
    #pragma unroll
    for (int p = 0; p < 8; ++p) {
      u64x2 kk = *(const u64x2*)(krowp + (((2 * p + hi) ^ (l31 & 7)) << 4));
      sacc = __builtin_amdgcn_mfma_f32_32x32x16_fp8_fp8((long)kk.x, qf8[2 * p],
                                                        sacc, 0, 0, 0);
      sacc = __builtin_amdgcn_mfma_f32_32x32x16_fp8_fp8((long)kk.y, qf8[2 * p + 1],
                                                        sacc, 0, 0, 0);
    }
    #pragma unroll
    for (int r = 0; r < 16; ++r) sacc[r] *= 0.0625f;  // undo Q x16 prescale

    // ---- in-register online softmax (col q = l31; sacc[r] = S^T[kv=crow(r,hi)][q])
    float pm = sacc[0];
    #pragma unroll
    for (int r = 1; r < 16; ++r) pm = fmaxf(pm, sacc[r]);
    pm = fmaxf(pm, sx32f(pm));  // full 32-kv row max for this tile

    if (!__all(pm - mrun <= 8.0f)) {   // defer-max (T13), THR=8 in log2 domain
      float mnew = fmaxf(mrun, pm);
      float al = exp2f(mrun - mnew);
      mrun = mnew;
      lrun *= al;
      #pragma unroll
      for (int r = 0; r < 16; ++r) {
        float ar = __shfl(al, (r & 3) + 8 * (r >> 2) + 4 * hi, 64);
        #pragma unroll
        for (int dt = 0; dt < 8; ++dt) o[dt][r] *= ar;
      }
    }

    // exp2 in place (sacc becomes P)
    float ls = 0.0f;
    #pragma unroll
    for (int r = 0; r < 16; ++r) { sacc[r] = exp2f(sacc[r] - mrun); ls += sacc[r]; }
    lrun += ls + sx32f(ls);

    // ---- pack P -> f16 A-frags in two batches
    half8 pa0, pa1;
    {
      uint32_t c0 = pkrtz(sacc[0], sacc[1]), c1 = pkrtz(sacc[2], sacc[3]);
      uint32_t c2 = pkrtz(sacc[4], sacc[5]), c3 = pkrtz(sacc[6], sacc[7]);
      uint32_t t0 = sx32u(c0), t1 = sx32u(c1), t2 = sx32u(c2), t3 = sx32u(c3);
      pa0 = __builtin_bit_cast(half8, (u32x4){
          hi ? t2 : c0, hi ? t3 : c1, hi ? c2 : t0, hi ? c3 : t1});
    }
    {
      uint32_t c0 = pkrtz(sacc[8], sacc[9]),  c1 = pkrtz(sacc[10], sacc[11]);
      uint32_t c2 = pkrtz(sacc[12], sacc[13]), c3 = pkrtz(sacc[14], sacc[15]);
      uint32_t t0 = sx32u(c0), t1 = sx32u(c1), t2 = sx32u(c2), t3 = sx32u(c3);
      pa1 = __builtin_bit_cast(half8, (u32x4){
          hi ? t2 : c0, hi ? t3 : c1, hi ? c2 : t0, hi ? c3 : t1});
    }

    // ---- PV: O[32q x 256d] += P[32q x 32kv] x V[32kv x 256d]  (f16, as R12)
    #pragma unroll
    for (int dt = 0; dt < 8; ++dt) {
      const char* vrow = vb + (dt * 32 + l31) * 64;
      const int vx = (dt * 32 + l31) & 3;
      half8 vf0 = *(const half8*)(vrow + (((0 + hi) ^ vx) << 4));
      half8 vf1 = *(const half8*)(vrow + (((2 + hi) ^ vx) << 4));
      o[dt] = __builtin_amdgcn_mfma_f32_32x32x16_f16(pa0, vf0, o[dt], 0, 0, 0);
      o[dt] = __builtin_amdgcn_mfma_f32_32x32x16_f16(pa1, vf1, o[dt], 0, 0, 0);
    }

    __syncthreads();  // reads of buf[cur] done + staging into buf[cur^1] drained
  }

  // ---- epilogue: store unnormalized partials (merge kernel combines halves)
  const size_t tok0 = (size_t)b * NSEQ + n0 + wid * 32;
  if (lane < 32) {
    mbuf[(size_t)kvh * NTOK + tok0 + l31] = mrun;
    lbuf[(size_t)kvh * NTOK + tok0 + l31] = lrun;
  }
  #pragma unroll
  for (int r = 0; r < 16; ++r) {
    int q = (r & 3) + 8 * (r >> 2) + 4 * hi;
    _Float16* prow = po + ((size_t)kvh * NTOK + tok0 + q) * CDIM + l31;
    #pragma unroll
    for (int dt = 0; dt < 8; ++dt)
      prow[dt * 32] = (_Float16)o[dt][r];
  }
}

// ---------------- merge: combine the two kv-half partials per token
__global__ __launch_bounds__(256) void merge_kernel(
    const _Float16* __restrict__ po, const float* __restrict__ mbuf,
    const float* __restrict__ lbuf, _Float16* __restrict__ og) {
  const int lane = threadIdx.x & 63;
  const size_t tok = (size_t)blockIdx.x * 4 + (threadIdx.x >> 6);
  const float m0 = mbuf[tok], m1 = mbuf[NTOK + tok];
  const float l0 = lbuf[tok], l1 = lbuf[NTOK + tok];
  const float mm = fmaxf(m0, m1);
  const float a0 = exp2f(m0 - mm), a1 = exp2f(m1 - mm);
  const float rl = 1.0f / (l0 * a0 + l1 * a1);
  const half4v o0 = ((const half4v*)(po + tok * CDIM))[lane];
  const half4v o1 = ((const half4v*)(po + ((size_t)NTOK + tok) * CDIM))[lane];
  half4v out;
  #pragma unroll
  for (int j = 0; j < 4; ++j)
    out[j] = (_Float16)(((float)o0[j] * a0 + (float)o1[j] * a1) * rl);
  ((half4v*)(og + tok * CDIM))[lane] = out;
}

// ---------------- launcher
extern "C" void kernel_launch(void* const* d_in, const int* in_sizes, int n_in,
                              void* d_out, int out_size, void* d_ws, size_t ws_size,
                              hipStream_t stream) {
  const float* x   = (const float*)d_in[0];
  const float* gam = (const float*)d_in[1];
  const float* bet = (const float*)d_in[2];
  const float* wq  = (const float*)d_in[3];
  const float* bq  = (const float*)d_in[4];
  const float* wk  = (const float*)d_in[5];
  const float* bk  = (const float*)d_in[6];
  const float* wv  = (const float*)d_in[7];
  const float* bv  = (const float*)d_in[8];
  const float* wp  = (const float*)d_in[9];
  const float* bp  = (const float*)d_in[10];
  float* out = (float*)d_out;

  char* ws = (char*)d_ws;
  _Float16* po  = (_Float16*)ws;                          // 32MB partial O x2 halves
  _Float16* xnh = (_Float16*)(ws + (32u << 20));          // 16MB f16 xn
  uint8_t*  qh8 = (uint8_t*)(ws + (48u << 20));           //  8MB q fp8 (scaled)
  uint8_t*  kh8 = (uint8_t*)(ws + (56u << 20));           //  8MB k fp8
  _Float16* vth = (_Float16*)(ws + (64u << 20));          // 16MB v^T f16 [b][c][n]
  _Float16* oh  = (_Float16*)(ws + (80u << 20));          // 16MB attn out (merged)
  float*    mbf = (float*)(ws + (96u << 20));             // 256KB m x2 halves
  float*    lbf = (float*)(ws + (96u << 20) + (1u << 18)); // 256KB l x2 halves

  (void)hipFuncSetAttribute((const void*)proj_kernel,
                            hipFuncAttributeMaxDynamicSharedMemorySize, 65536);
  (void)hipFuncSetAttribute((const void*)attn_kernel,
                            hipFuncAttributeMaxDynamicSharedMemorySize, ATTN_LDS);

  ln_kernel<<<NTOK / 4, 256, 0, stream>>>(x, gam, bet, xnh);
  proj_kernel<<<dim3(64, 4, 3), 256, 65536, stream>>>(
      xnh, wq, bq, wk, bk, wv, bv, wp, bp, qh8, kh8, vth, xnh, out, 0);
  attn_kernel<<<512, 256, ATTN_LDS, stream>>>(qh8, kh8, vth, po, mbf, lbf);
  merge_kernel<<<NTOK / 4, 256, 0, stream>>>(po, mbf, lbf, oh);
  proj_kernel<<<dim3(64, 4, 1), 256, 65536, stream>>>(
      oh, wq, bq, wk, bk, wv, bv, wp, bp, qh8, kh8, vth, xnh, out, 3);
}

// Round 14
// 193.170 us; speedup vs baseline: 1.6610x; 1.1823x over previous
//
#include <hip/hip_runtime.h>
#include <cstdint>

#define NB    8
#define NSEQ  4096
#define CDIM  256
#define NTOK  (NB*NSEQ)

typedef _Float16 half8  __attribute__((ext_vector_type(8)));
typedef _Float16 half4v __attribute__((ext_vector_type(4)));
typedef float    f32x4  __attribute__((ext_vector_type(4)));
typedef float    f32x16 __attribute__((ext_vector_type(16)));
typedef uint32_t u32x4  __attribute__((ext_vector_type(4)));
typedef unsigned long u64x2 __attribute__((ext_vector_type(2)));

typedef unsigned int u32_g __attribute__((address_space(1)));
typedef unsigned int u32_l __attribute__((address_space(3)));

// direct global->LDS, 16B per lane; LDS dest = wave-uniform base + lane*16
__device__ __forceinline__ void gload_lds16(const void* g, void* l) {
  __builtin_amdgcn_global_load_lds((u32_g*)(uintptr_t)g,
                                   (u32_l*)(uint32_t)(uintptr_t)l, 16, 0, 0);
}

__device__ __forceinline__ uint8_t to_fp8(float v) {
  return (uint8_t)(__builtin_amdgcn_cvt_pk_fp8_f32(v, v, 0, false) & 0xff);
}
// pack 4 floats -> 4 fp8 bytes in one u32
__device__ __forceinline__ uint32_t pk4_fp8(float a, float b, float c, float d) {
  uint32_t w = (uint32_t)__builtin_amdgcn_cvt_pk_fp8_f32(a, b, 0, false);
  return (uint32_t)__builtin_amdgcn_cvt_pk_fp8_f32(c, d, (int)w, true);
}
// lane^32 exchange via shfl (semantics-certain)
__device__ __forceinline__ float sx32f(float v) { return __shfl_xor(v, 32, 64); }
__device__ __forceinline__ uint32_t sx32u(uint32_t v) {
  return (uint32_t)__shfl_xor((int)v, 32, 64);
}

// ---------------- LayerNorm: one wave per token; f16 xn only
__global__ __launch_bounds__(256) void ln_kernel(
    const float* __restrict__ x, const float* __restrict__ gam,
    const float* __restrict__ bet, _Float16* __restrict__ xnh) {
  const int lane = threadIdx.x & 63;
  const size_t tok = (size_t)blockIdx.x * 4 + (threadIdx.x >> 6);
  const float4 v = ((const float4*)(x + tok * CDIM))[lane];
  float s  = v.x + v.y + v.z + v.w;
  float s2 = v.x*v.x + v.y*v.y + v.z*v.z + v.w*v.w;
  #pragma unroll
  for (int m = 1; m < 64; m <<= 1) {
    s  += __shfl_xor(s,  m, 64);
    s2 += __shfl_xor(s2, m, 64);
  }
  const float mean = s * (1.0f / CDIM);
  const float rstd = rsqrtf(s2 * (1.0f / CDIM) - mean * mean + 1e-3f);
  const float4 gv = ((const float4*)gam)[lane];
  const float4 bv = ((const float4*)bet)[lane];
  half4v h;
  h[0] = (_Float16)((v.x - mean) * rstd * gv.x + bv.x);
  h[1] = (_Float16)((v.y - mean) * rstd * gv.y + bv.y);
  h[2] = (_Float16)((v.z - mean) * rstd * gv.z + bv.z);
  h[3] = (_Float16)((v.w - mean) * rstd * gv.w + bv.w);
  ((half4v*)(xnh + tok * CDIM))[lane] = h;
}

// ---------------- projection GEMM
// modes: 0=Q (fp8, log2e folded), 1=K (fp8), 2=V (fp8 chunked [b][nblk][512slot][16B]),
//        3=P (fp32 + residual).
// Q/K fp8 rows hi-split: byte(m,hi,j) = (m>>1)*32 + hi*16 + (m&1)*8 + j.
// V chunk layout: slot(d,sel) = (d>>3)*16 + sel*8 + (d&7); chunk bytes:
//   sel=0 = [kv0-7 | kv16-23], sel=1 = [kv8-15 | kv24-31] (kv = token & 31).
__global__ __launch_bounds__(256, 2) void proj_kernel(
    const _Float16* __restrict__ inh,
    const float* __restrict__ wq_, const float* __restrict__ bq_,
    const float* __restrict__ wk_, const float* __restrict__ bk_,
    const float* __restrict__ wv_, const float* __restrict__ bv_,
    const float* __restrict__ wp_, const float* __restrict__ bp_,
    uint8_t* __restrict__ qg8, uint8_t* __restrict__ kg8,
    uint8_t* __restrict__ vt8,
    const _Float16* __restrict__ residh, float* __restrict__ outf,
    int mode_base) {
  extern __shared__ char smem[];
  const int mode = mode_base + blockIdx.z;
  const float* wsel = (mode == 0) ? wq_ : (mode == 1) ? wk_ : (mode == 2) ? wv_ : wp_;
  const float* bsel = (mode == 0) ? bq_ : (mode == 1) ? bk_ : (mode == 2) ? bv_ : bp_;

  const int tid = threadIdx.x;
  const int lane = tid & 63;
  const int wid  = tid >> 6;     // 0..3
  const int g    = lane >> 4;    // 0..3
  const int lr   = lane & 15;
  const int jstrip = blockIdx.y; // 0..3
  const size_t tok0 = (size_t)blockIdx.x * 512;

  char* wt   = smem;             // [64 j][256 c] f16, XOR-swizzled (32KB)
  char* tile = smem + 32768;     // [64 tok][256 c] f16, swizzled (32KB)

  for (int i = 0; i < 64; ++i) {
    int idx = i * 256 + tid;
    int c = idx >> 6, j = idx & 63;
    float val = wsel[(size_t)c * CDIM + jstrip * 64 + j];
    *(_Float16*)(wt + j * 512 + ((((c >> 3) ^ (j & 7))) << 4) + ((c & 7) << 1)) =
        (_Float16)val;
  }
  float bjv[4];
  #pragma unroll
  for (int jc = 0; jc < 4; ++jc) bjv[jc] = bsel[jstrip * 64 + jc * 16 + lr];
  __syncthreads();

  for (int t = 0; t < 8; ++t) {
    const size_t trow0 = tok0 + t * 64;
    #pragma unroll
    for (int i = 0; i < 8; ++i) {
      int pbase = (i * 4 + wid) * 64;
      int p = pbase + lane;
      int row = p >> 5, sl = p & 31;
      gload_lds16(inh + (trow0 + row) * CDIM + (size_t)((sl ^ (row & 7)) * 8),
                  tile + pbase * 16);
    }
    __syncthreads();

    f32x4 acc[4] = {{0,0,0,0},{0,0,0,0},{0,0,0,0},{0,0,0,0}};
    #pragma unroll
    for (int kc = 0; kc < 8; ++kc) {
      half8 a = *(const half8*)(tile + (wid * 16 + lr) * 512 +
                                ((((kc << 2) | g) ^ (lr & 7)) << 4));
      #pragma unroll
      for (int jc = 0; jc < 4; ++jc) {
        half8 bf = *(const half8*)(wt + (jc * 16 + lr) * 512 +
                                   ((((kc << 2) | g) ^ (lr & 7)) << 4));
        acc[jc] = __builtin_amdgcn_mfma_f32_16x16x32_f16(a, bf, acc[jc], 0, 0, 0);
      }
    }

    if (mode == 3) {
      #pragma unroll
      for (int jc = 0; jc < 4; ++jc) {
        #pragma unroll
        for (int r = 0; r < 4; ++r) {
          size_t row = trow0 + wid * 16 + g * 4 + r;
          size_t off = row * CDIM + jstrip * 64 + jc * 16 + lr;
          outf[off] = acc[jc][r] + bjv[jc] + (float)residh[off];
        }
      }
    } else if (mode <= 1) {
      // fp8 path (Q: scale log2(e); K: 1.0), hi-split byte layout
      const float csc = (mode == 0) ? 1.44269504f : 1.0f;
      __syncthreads();
      uint8_t* ot8 = (uint8_t*)tile;  // [64 tok][64 B]
      #pragma unroll
      for (int jc = 0; jc < 4; ++jc) {
        #pragma unroll
        for (int r = 0; r < 4; ++r) {
          int row = wid * 16 + g * 4 + r;
          int pos = (jc >> 1) * 32 + (lr >> 3) * 16 + (jc & 1) * 8 + (lr & 7);
          ot8[row * 64 + pos] = to_fp8((acc[jc][r] + bjv[jc]) * csc);
        }
      }
      __syncthreads();
      uint8_t* dst8 = (mode == 0) ? qg8 : kg8;
      int row = tid >> 2, s = tid & 3;   // 64 rows x 4 x 16B
      *(u32x4*)(dst8 + (trow0 + row) * 256 + jstrip * 64 + s * 16) =
          *(const u32x4*)(ot8 + row * 64 + s * 16);
    } else {
      // V fp8, chunked slot layout (attn stages it as an identity copy)
      __syncthreads();
      uint8_t* ot8 = (uint8_t*)tile;  // [2 kvblk][128 slots][16B] = 4KB
      #pragma unroll
      for (int jc = 0; jc < 4; ++jc) {
        #pragma unroll
        for (int r = 0; r < 4; ++r) {
          int tok64 = wid * 16 + g * 4 + r;
          int kvblk = tok64 >> 5, kv = tok64 & 31;
          int dl = jc * 16 + lr;
          int sel = (kv >> 3) & 1;
          int pos = (kv & 7) + ((kv >> 4) & 1) * 8;
          int sloc = (dl >> 3) * 16 + sel * 8 + (dl & 7);
          ot8[kvblk * 2048 + sloc * 16 + pos] = to_fp8(acc[jc][r] + bjv[jc]);
        }
      }
      __syncthreads();
      int kvblk = tid >> 7, sl = tid & 127;
      size_t bb = trow0 >> 12;
      size_t nblk = ((trow0 & 4095) >> 5) + kvblk;
      *(u32x4*)(vt8 + ((bb * 128 + nblk) * 512 + jstrip * 128 + sl) * 16) =
          *(const u32x4*)(ot8 + kvblk * 2048 + sl * 16);
    }
    __syncthreads();
  }
}

// ---------------- flash attention v12: split-KV + full fp8 operands
// S: mfma_32x32x16_fp8_fp8 (8 LDS reads). PV: fp8 P (in-reg cvt) x fp8 V,
// one b128 read = BOTH B-frags per dt -> 8 reads (was 16). 16 reads/wave/iter.
// LDS: K dbuf 2x8KB @0, V dbuf 2x8KB @16384 = 32768 B; 2 blocks/CU.
#define ATTN_LDS 32768

__global__ __launch_bounds__(256)
__attribute__((amdgpu_waves_per_eu(2, 2)))
void attn_kernel(
    const uint8_t* __restrict__ qg8, const uint8_t* __restrict__ kg8,
    const uint8_t* __restrict__ vt8, _Float16* __restrict__ po,
    float* __restrict__ mbuf, float* __restrict__ lbuf) {
  extern __shared__ char smem[];

  const int tid  = threadIdx.x;
  const int lane = tid & 63;
  const int wid  = tid >> 6;    // 0..3 = q-group
  const int l31  = lane & 31;
  const int hi   = lane >> 5;   // 0/1
  const int bid  = blockIdx.x;
  const int b    = bid & 7;               // XCD-affine batch
  const int kvh  = (bid >> 3) & 1;        // kv half
  const int n0   = (bid >> 4) * 128;      // q-tile base
  const int kvbase = kvh * 2048;

  // ---- prologue: stage tile 0 (K fp8 [32][256B] + V fp8 chunked 8KB) into buf 0
  #pragma unroll
  for (int i = 0; i < 2; ++i) {
    int slot = i * 256 + tid;
    int row = slot >> 4, s = slot & 15;
    gload_lds16(kg8 + ((size_t)(b * NSEQ + kvbase + row)) * 256 + ((s ^ (row & 7)) << 4),
                smem + slot * 16);
    gload_lds16(vt8 + ((size_t)(b * 128 + kvh * 64) * 512 + slot) * 16,
                smem + 16384 + slot * 16);
  }

  // ---- Q fragments (fp8): lane holds Q[q=l31][c = m*16 + hi*8 + j], 8 B per frag
  long qf8[16];
  {
    const uint8_t* qp8 = qg8 + ((size_t)(b * NSEQ + n0 + wid * 32 + l31)) * 256;
    #pragma unroll
    for (int p = 0; p < 8; ++p) {
      u64x2 qq = *(const u64x2*)(qp8 + (2 * p + hi) * 16);
      qf8[2 * p]     = (long)qq.x;
      qf8[2 * p + 1] = (long)qq.y;
    }
  }

  f32x16 o[8];  // O[q=(r&3)+8*(r>>2)+4*hi][d=dt*32+l31], f32 (unnormalized)
  #pragma unroll
  for (int dt = 0; dt < 8; ++dt)
    #pragma unroll
    for (int r = 0; r < 16; ++r) o[dt][r] = 0.0f;
  float mrun = -1e30f, lrun = 0.0f;

  __syncthreads();  // prologue staging drained

  for (int t = 0; t < 64; ++t) {
    const int cur = t & 1;
    const char* kb = smem + cur * 8192;
    const char* vb = smem + 16384 + cur * 8192;

    // issue next tile's staging into the other buffer
    if (t < 63) {
      const int kv0n = kvbase + (t + 1) * 32;
      char* kn = smem + (cur ^ 1) * 8192;
      char* vn = smem + 16384 + (cur ^ 1) * 8192;
      #pragma unroll
      for (int i = 0; i < 2; ++i) {
        int slot = i * 256 + tid;
        int row = slot >> 4, s = slot & 15;
        gload_lds16(kg8 + ((size_t)(b * NSEQ + kv0n + row)) * 256 + ((s ^ (row & 7)) << 4),
                    kn + slot * 16);
        gload_lds16(vt8 + ((size_t)(b * 128 + kvh * 64 + t + 1) * 512 + slot) * 16,
                    vn + slot * 16);
      }
    }

    // ---- S^T = K x Q^T (fp8): 16 MFMA, 8 LDS reads (b128 = 2 A-frags)
    f32x16 sacc;
    #pragma unroll
    for (int r = 0; r < 16; ++r) sacc[r] = 0.0f;
    const char* krowp = kb + l31 * 256;
    #pragma unroll
    for (int p = 0; p < 8; ++p) {
      u64x2 kk = *(const u64x2*)(krowp + (((2 * p + hi) ^ (l31 & 7)) << 4));
      sacc = __builtin_amdgcn_mfma_f32_32x32x16_fp8_fp8((long)kk.x, qf8[2 * p],
                                                        sacc, 0, 0, 0);
      sacc = __builtin_amdgcn_mfma_f32_32x32x16_fp8_fp8((long)kk.y, qf8[2 * p + 1],
                                                        sacc, 0, 0, 0);
    }
    #pragma unroll
    for (int r = 0; r < 16; ++r) sacc[r] *= 0.0625f;  // attention scale 1/16

    // ---- in-register online softmax (col q = l31; sacc[r] = S^T[kv=crow(r,hi)][q])
    float pm = sacc[0];
    #pragma unroll
    for (int r = 1; r < 16; ++r) pm = fmaxf(pm, sacc[r]);
    pm = fmaxf(pm, sx32f(pm));  // full 32-kv row max for this tile

    if (!__all(pm - mrun <= 8.0f)) {   // defer-max (T13), THR=8 in log2 domain
      float mnew = fmaxf(mrun, pm);
      float al = exp2f(mrun - mnew);
      mrun = mnew;
      lrun *= al;
      #pragma unroll
      for (int r = 0; r < 16; ++r) {
        float ar = __shfl(al, (r & 3) + 8 * (r >> 2) + 4 * hi, 64);
        #pragma unroll
        for (int dt = 0; dt < 8; ++dt) o[dt][r] *= ar;
      }
    }

    // exp2 in place (sacc becomes P)
    float ls = 0.0f;
    #pragma unroll
    for (int r = 0; r < 16; ++r) { sacc[r] = exp2f(sacc[r] - mrun); ls += sacc[r]; }
    lrun += ls + sx32f(ls);

    // ---- pack P -> fp8 A-frags: 8 cvt_pk + 4 lane^32 shfl + select
    // w_i = fp8(p[4i..4i+3]); own kv = crow(r,hi).
    uint32_t w0 = pk4_fp8(sacc[0],  sacc[1],  sacc[2],  sacc[3]);
    uint32_t w1 = pk4_fp8(sacc[4],  sacc[5],  sacc[6],  sacc[7]);
    uint32_t w2 = pk4_fp8(sacc[8],  sacc[9],  sacc[10], sacc[11]);
    uint32_t w3 = pk4_fp8(sacc[12], sacc[13], sacc[14], sacc[15]);
    uint32_t t0 = sx32u(w0), t1 = sx32u(w1), t2 = sx32u(w2), t3 = sx32u(w3);
    long pa0 = (long)(((uint64_t)(hi ? w1 : t0) << 32) | (uint32_t)(hi ? t1 : w0));
    long pa1 = (long)(((uint64_t)(hi ? w3 : t2) << 32) | (uint32_t)(hi ? t3 : w2));

    // ---- PV: O += P x V (fp8): 16 MFMA, 8 LDS reads (b128 = both B-frags)
    #pragma unroll
    for (int dt = 0; dt < 8; ++dt) {
      const int dv = dt * 32 + l31;
      u64x2 vv = *(const u64x2*)(vb + (dv >> 3) * 256 + hi * 128 + (dv & 7) * 16);
      o[dt] = __builtin_amdgcn_mfma_f32_32x32x16_fp8_fp8(pa0, (long)vv.x, o[dt], 0, 0, 0);
      o[dt] = __builtin_amdgcn_mfma_f32_32x32x16_fp8_fp8(pa1, (long)vv.y, o[dt], 0, 0, 0);
    }

    __syncthreads();  // reads of buf[cur] done + staging into buf[cur^1] drained
  }

  // ---- epilogue: store unnormalized partials (merge kernel combines halves)
  const size_t tok0 = (size_t)b * NSEQ + n0 + wid * 32;
  if (lane < 32) {
    mbuf[(size_t)kvh * NTOK + tok0 + l31] = mrun;
    lbuf[(size_t)kvh * NTOK + tok0 + l31] = lrun;
  }
  #pragma unroll
  for (int r = 0; r < 16; ++r) {
    int q = (r & 3) + 8 * (r >> 2) + 4 * hi;
    _Float16* prow = po + ((size_t)kvh * NTOK + tok0 + q) * CDIM + l31;
    #pragma unroll
    for (int dt = 0; dt < 8; ++dt)
      prow[dt * 32] = (_Float16)o[dt][r];
  }
}

// ---------------- merge: combine the two kv-half partials per token
__global__ __launch_bounds__(256) void merge_kernel(
    const _Float16* __restrict__ po, const float* __restrict__ mbuf,
    const float* __restrict__ lbuf, _Float16* __restrict__ og) {
  const int lane = threadIdx.x & 63;
  const size_t tok = (size_t)blockIdx.x * 4 + (threadIdx.x >> 6);
  const float m0 = mbuf[tok], m1 = mbuf[NTOK + tok];
  const float l0 = lbuf[tok], l1 = lbuf[NTOK + tok];
  const float mm = fmaxf(m0, m1);
  const float a0 = exp2f(m0 - mm), a1 = exp2f(m1 - mm);
  const float rl = 1.0f / (l0 * a0 + l1 * a1);
  const half4v o0 = ((const half4v*)(po + tok * CDIM))[lane];
  const half4v o1 = ((const half4v*)(po + ((size_t)NTOK + tok) * CDIM))[lane];
  half4v out;
  #pragma unroll
  for (int j = 0; j < 4; ++j)
    out[j] = (_Float16)(((float)o0[j] * a0 + (float)o1[j] * a1) * rl);
  ((half4v*)(og + tok * CDIM))[lane] = out;
}

// ---------------- launcher
extern "C" void kernel_launch(void* const* d_in, const int* in_sizes, int n_in,
                              void* d_out, int out_size, void* d_ws, size_t ws_size,
                              hipStream_t stream) {
  const float* x   = (const float*)d_in[0];
  const float* gam = (const float*)d_in[1];
  const float* bet = (const float*)d_in[2];
  const float* wq  = (const float*)d_in[3];
  const float* bq  = (const float*)d_in[4];
  const float* wk  = (const float*)d_in[5];
  const float* bk  = (const float*)d_in[6];
  const float* wv  = (const float*)d_in[7];
  const float* bv  = (const float*)d_in[8];
  const float* wp  = (const float*)d_in[9];
  const float* bp  = (const float*)d_in[10];
  float* out = (float*)d_out;

  char* ws = (char*)d_ws;
  _Float16* po  = (_Float16*)ws;                          // 32MB partial O x2 halves
  _Float16* xnh = (_Float16*)(ws + (32u << 20));          // 16MB f16 xn
  uint8_t*  qh8 = (uint8_t*)(ws + (48u << 20));           //  8MB q fp8 (scaled)
  uint8_t*  kh8 = (uint8_t*)(ws + (56u << 20));           //  8MB k fp8
  uint8_t*  vt8 = (uint8_t*)(ws + (64u << 20));           //  8MB v fp8 chunked
  _Float16* oh  = (_Float16*)(ws + (72u << 20));          // 16MB attn out (merged)
  float*    mbf = (float*)(ws + (88u << 20));             // 256KB m x2 halves
  float*    lbf = (float*)(ws + (88u << 20) + (1u << 18)); // 256KB l x2 halves

  (void)hipFuncSetAttribute((const void*)proj_kernel,
                            hipFuncAttributeMaxDynamicSharedMemorySize, 65536);
  (void)hipFuncSetAttribute((const void*)attn_kernel,
                            hipFuncAttributeMaxDynamicSharedMemorySize, ATTN_LDS);

  ln_kernel<<<NTOK / 4, 256, 0, stream>>>(x, gam, bet, xnh);
  proj_kernel<<<dim3(64, 4, 3), 256, 65536, stream>>>(
      xnh, wq, bq, wk, bk, wv, bv, wp, bp, qh8, kh8, vt8, xnh, out, 0);
  attn_kernel<<<512, 256, ATTN_LDS, stream>>>(qh8, kh8, vt8, po, mbf, lbf);
  merge_kernel<<<NTOK / 4, 256, 0, stream>>>(po, mbf, lbf, oh);
  proj_kernel<<<dim3(64, 4, 1), 256, 65536, stream>>>(
      oh, wq, bq, wk, bk, wv, bv, wp, bp, qh8, kh8, vt8, xnh, out, 3);
}